// Round 6
// baseline (381.654 us; speedup 1.0000x reference)
//
#include <hip/hip_runtime.h>
#include <hip/hip_bf16.h>

// DGCF forward, MI355X. f32 in/out.
// R11: bucketed CSR build. R12: all-lane k_iter epilogue + out restructure.
// R13: fuse scores/softmax/A-update/D-rowsum into k_iter.
// R14: software-pipelined 16-edge chunks (2 serial latencies/row).
// R15 (reverted): f32 tables doubled FETCH, random-gather path can't stream.
// R16: bf16 tables + degree-adaptive chunk depth + 32-bit indices.
// R17: (a) scores dot via v_dot2_f32_bf16 (2 insts per 4 dims, no unpack;
// fn packed to bf16 once per node — numerically = pre-R13 bf16 fnb);
// (b) CSR count/scatter at EPB=1280 (2x waves for the latency-bound phases).
#define NUSER 50000
#define NITEM 50000
#define NN    100000          // NUSER+NITEM
#define NNZ_  1000000
#define DIM_  64
#define NBLK  391             // ceil_div(NN,256) == bucket count
#define EPB   1280            // edges per count/scatter block (782*1280 >= NNZ)

#define FL_SVC    1   // svals == 0.25 (iteration 0)
#define FL_SC     2   // fused scores: dot(fn, te[tail]) -> A -> softmax -> svals, d_next
#define FL_NEXT   8   // write ego_next / te_next
#define FL_FIN    16  // out = (out + ego_row + fn) / 3
#define FL_ACONST 32  // scores: A_old == 1
#define FL_ASTORE 64  // scores: store A_new

static inline int ceil_div(int a, int b) { return (a + b - 1) / b; }

static __device__ inline float bf2f(unsigned short u) {
    return __uint_as_float(((unsigned int)u) << 16);
}
static __device__ inline unsigned short f2bf(float f) {
    unsigned int x = __float_as_uint(f);
    x += 0x7fffu + ((x >> 16) & 1u);
    return (unsigned short)(x >> 16);
}

// packed bf16x2 dot: c += a.lo*b.lo + a.hi*b.hi (hw v_dot2_f32_bf16 if present)
#if __has_builtin(__builtin_amdgcn_fdot2_f32_bf16)
typedef __bf16 bf16x2_t __attribute__((ext_vector_type(2)));
static __device__ inline float dot2bf(unsigned int a, unsigned int b, float c) {
    return __builtin_amdgcn_fdot2_f32_bf16(__builtin_bit_cast(bf16x2_t, a),
                                           __builtin_bit_cast(bf16x2_t, b), c, false);
}
#else
static __device__ inline float dot2bf(unsigned int a, unsigned int b, float c) {
    return c + bf2f((unsigned short)(a & 0xffffu)) * bf2f((unsigned short)(b & 0xffffu))
             + bf2f((unsigned short)(a >> 16)) * bf2f((unsigned short)(b >> 16));
}
#endif

// ego = concat(user,item) bf16; te = tanh(l2norm chunk16) bf16; out = ego f32.
__global__ void k_init(const float* __restrict__ eu, const float* __restrict__ ei,
                       unsigned short* __restrict__ ego, unsigned short* __restrict__ te,
                       float* __restrict__ out) {
    int i = blockIdx.x * 256 + threadIdx.x;
    if (i >= NN * DIM_) return;
    float v = (i < NUSER * DIM_) ? eu[i] : ei[i - NUSER * DIM_];
    out[i] = v;
    ego[i] = f2bf(v);
    float s = v * v;
    s += __shfl_xor(s, 1); s += __shfl_xor(s, 2);
    s += __shfl_xor(s, 4); s += __shfl_xor(s, 8);
    float nrm = v / fmaxf(sqrtf(s), 1e-12f);
    float ex = __expf(2.0f * nrm);
    te[i] = f2bf((ex - 1.0f) / (ex + 1.0f));
}

// ---- bucketed CSR build (once per launch) ----
__global__ void k_bcount(const int* __restrict__ head, int* __restrict__ bcount) {
    __shared__ int cnt[NBLK];
    int tid = threadIdx.x;
    for (int i = tid; i < NBLK; i += 256) cnt[i] = 0;
    __syncthreads();
    int e0 = blockIdx.x * EPB;
    int e1 = min(e0 + EPB, NNZ_);
    for (int e = e0 + tid; e < e1; e += 256)
        atomicAdd(&cnt[head[e] >> 8], 1);
    __syncthreads();
    for (int i = tid; i < NBLK; i += 256)
        if (cnt[i]) atomicAdd(&bcount[i], cnt[i]);
}

__global__ void k_bscan(const int* __restrict__ bcount, int* __restrict__ bucket_base,
                        int* __restrict__ bucket_cursor, int* __restrict__ row_start_end) {
    __shared__ int sh[512];
    int t = threadIdx.x;
    int v = (t < NBLK) ? bcount[t] : 0;
    sh[t] = v;
    __syncthreads();
    for (int off = 1; off < 512; off <<= 1) {
        int u = 0;
        if (t >= off) u = sh[t - off];
        __syncthreads();
        sh[t] += u;
        __syncthreads();
    }
    if (t < NBLK) {
        int base = sh[t] - v;
        bucket_base[t] = base;
        bucket_cursor[t] = base;
    }
    if (t == 511) {
        bucket_base[NBLK] = sh[511];    // == NNZ_
        row_start_end[0] = sh[511];
    }
}

__global__ void k_binscat(const int* __restrict__ head, const int* __restrict__ tail,
                          int* __restrict__ bucket_cursor, int2* __restrict__ bin) {
    __shared__ int cnt[NBLK];
    __shared__ int chunk[NBLK];
    int tid = threadIdx.x;
    for (int i = tid; i < NBLK; i += 256) cnt[i] = 0;
    __syncthreads();
    int e0 = blockIdx.x * EPB;
    int e1 = min(e0 + EPB, NNZ_);
    for (int e = e0 + tid; e < e1; e += 256)
        atomicAdd(&cnt[head[e] >> 8], 1);
    __syncthreads();
    for (int i = tid; i < NBLK; i += 256) {
        chunk[i] = cnt[i] ? atomicAdd(&bucket_cursor[i], cnt[i]) : 0;
        cnt[i] = 0;   // reuse as local cursor
    }
    __syncthreads();
    for (int e = e0 + tid; e < e1; e += 256) {
        int h = head[e], t = tail[e];
        int b = h >> 8;
        int off = atomicAdd(&cnt[b], 1);
        bin[chunk[b] + off] = make_int2(h, t);
    }
}

__global__ void k_bucket(const int2* __restrict__ bin, const int* __restrict__ bucket_base,
                         int* __restrict__ row_start, float4* __restrict__ d4a,
                         int* __restrict__ csr_tail) {
    __shared__ int deg[256];
    __shared__ int sh[256];
    __shared__ int cur[256];
    int tid = threadIdx.x;
    int b = blockIdx.x;
    int n0 = b << 8;
    int e0 = bucket_base[b], e1 = bucket_base[b + 1];
    deg[tid] = 0;
    __syncthreads();
    for (int e = e0 + tid; e < e1; e += 256)
        atomicAdd(&deg[bin[e].x - n0], 1);
    __syncthreads();
    int myDeg = deg[tid];
    sh[tid] = myDeg;
    __syncthreads();
    for (int off = 1; off < 256; off <<= 1) {
        int u = 0;
        if (tid >= off) u = sh[tid - off];
        __syncthreads();
        sh[tid] += u;
        __syncthreads();
    }
    int loff = sh[tid] - myDeg;   // exclusive local offset
    int n = n0 + tid;
    if (n < NN) {
        row_start[n] = e0 + loff;
        float dd = (myDeg > 0) ? 2.0f / sqrtf((float)myDeg) : 0.0f;
        d4a[n] = make_float4(dd, dd, dd, dd);
    }
    cur[tid] = e0 + loff;
    __syncthreads();
    for (int e = e0 + tid; e < e1; e += 256) {
        int2 p = bin[e];
        int pos = atomicAdd(&cur[p.x - n0], 1);
        csr_tail[pos] = p.y;
    }
}

// ---- fused walk + scores body, NJ = chunk depth in 4-edge steps ----
// lane = 16*q + l: q = edge slot (0..3), l = dim quad (dims 4l..4l+3), f = l>>2.
// All indices 32-bit (max byte offset 12.8 MB << 2^31).
template<int FLAGS, int NJ>
static __device__ __forceinline__ void iter_body(
    int n, int lane, int q, int l, int f, int r0, int r1,
    unsigned short* __restrict__ svals, const float* __restrict__ d4c,
    const unsigned short* __restrict__ ego, const unsigned short* __restrict__ te,
    const int* __restrict__ csr_tail,
    float* __restrict__ A4, float* __restrict__ d4n,
    float* __restrict__ out,
    unsigned short* __restrict__ egon, unsigned short* __restrict__ ten)
{
    float ax = 0.f, ay = 0.f, az = 0.f, aw = 0.f;

    // ---- chunk 0: edges r0+q+4j, j=0..NJ-1 (te cached for scores phase) ----
    int ct[NJ]; float cw[NJ]; float ca[NJ]; uint2 cv[NJ]; float cd[NJ];
    int eb = r0 + q;
    // level 0: independent loads, issued back-to-back
#pragma unroll
    for (int j = 0; j < NJ; ++j) {
        int i = eb + 4 * j;
        bool v = (i < r1);
        int ic = v ? i : 0;
        ct[j] = csr_tail[ic];
        float w;
        if (FLAGS & FL_SVC) w = 0.25f;
        else w = bf2f(svals[ic * 4 + f]);
        cw[j] = v ? w : 0.f;
        if ((FLAGS & FL_SC) && !(FLAGS & FL_ACONST))
            ca[j] = A4[ic * 4 + f];
    }
    // level 1: gathers depending only on tails, issued back-to-back
#pragma unroll
    for (int j = 0; j < NJ; ++j) {
        int t = ct[j];
        cd[j] = d4c[t * 4 + f];
        if (FLAGS & FL_SC)
            cv[j] = *(const uint2*)(te + t * 64 + 4 * l);
    }
#pragma unroll
    for (int j = 0; j < NJ; ++j) {
        ushort4 u = *(const ushort4*)(ego + ct[j] * 64 + 4 * l);
        float w = cw[j] * cd[j];
        ax += w * bf2f(u.x); ay += w * bf2f(u.y);
        az += w * bf2f(u.z); aw += w * bf2f(u.w);
    }

    // ---- remainder chunks (deg > 16), only reachable in the NJ==4 arm ----
    if (NJ == 4) {
        for (int base = r0 + 16; base < r1; base += 16) {
            int tj[4]; float wj[4];
#pragma unroll
            for (int j = 0; j < 4; ++j) {
                int i = base + q + 4 * j;
                bool v = (i < r1);
                int ic = v ? i : 0;
                tj[j] = csr_tail[ic];
                float w;
                if (FLAGS & FL_SVC) w = 0.25f;
                else w = bf2f(svals[ic * 4 + f]);
                wj[j] = v ? w : 0.f;
            }
#pragma unroll
            for (int j = 0; j < 4; ++j) {
                int t = tj[j];
                float w = wj[j] * d4c[t * 4 + f];
                ushort4 u = *(const ushort4*)(ego + t * 64 + 4 * l);
                ax += w * bf2f(u.x); ay += w * bf2f(u.y);
                az += w * bf2f(u.z); aw += w * bf2f(u.w);
            }
        }
    }

    // reduce over edge slots -> each lane holds full sums for its dim quad
    ax += __shfl_xor(ax, 16); ax += __shfl_xor(ax, 32);
    ay += __shfl_xor(ay, 16); ay += __shfl_xor(ay, 32);
    az += __shfl_xor(az, 16); az += __shfl_xor(az, 32);
    aw += __shfl_xor(aw, 16); aw += __shfl_xor(aw, 32);

    // l2 norm over the 16-dim factor chunk (quad layout: reduce over l&3)
    float s = ax * ax + ay * ay + az * az + aw * aw;
    s += __shfl_xor(s, 1); s += __shfl_xor(s, 2);
    float inv = 1.0f / fmaxf(sqrtf(s), 1e-12f);
    float fx = ax * inv, fy = ay * inv, fz = az * inv, fw = aw * inv;

    if (FLAGS & (FL_NEXT | FL_FIN)) {
        // redistribute: lane p takes dim p (= component p&3 of lane p>>2's quad)
        int src = lane >> 2;
        float t0r = __shfl(fx, src), t1r = __shfl(fy, src);
        float t2r = __shfl(fz, src), t3r = __shfl(fw, src);
        float y = (lane & 2) ? ((lane & 1) ? t3r : t2r) : ((lane & 1) ? t1r : t0r);
        int base = n * 64 + lane;
        if (FLAGS & FL_FIN) {
            // out holds init; walk table row n holds bf16 fn1 -> 3-term mean
            out[base] = (out[base] + bf2f(ego[base]) + y) * (1.0f / 3.0f);
        }
        if (FLAGS & FL_NEXT) {
            egon[base] = f2bf(y);
            float e2 = __expf(2.0f * y);
            ten[base] = f2bf((e2 - 1.0f) / (e2 + 1.0f));
        }
    }

    if (FLAGS & FL_SC) {
        // pack fn once per node: lane's 4 dims -> two bf16x2 dwords
        unsigned int p01 = ((unsigned int)f2bf(fy) << 16) | f2bf(fx);
        unsigned int p23 = ((unsigned int)f2bf(fw) << 16) | f2bf(fz);
        float accs = 0.f;   // rowsum of svals for this lane's factor f
        // cached chunk 0: pure register compute
#pragma unroll
        for (int j = 0; j < NJ; ++j) {
            int i = eb + 4 * j;
            bool v = (i < r1);
            float dot = dot2bf(cv[j].y, p23, dot2bf(cv[j].x, p01, 0.0f));
            dot += __shfl_xor(dot, 1); dot += __shfl_xor(dot, 2);
            float a = (FLAGS & FL_ACONST) ? 1.0f : ca[j];
            a += dot;
            if ((FLAGS & FL_ASTORE) && v && (l & 3) == 0)
                A4[i * 4 + f] = a;
            float ex = __expf(a);
            float sum = ex;
            sum += __shfl_xor(sum, 4); sum += __shfl_xor(sum, 8);
            float sv = ex / sum;
            if (v && (l & 3) == 0)
                svals[i * 4 + f] = f2bf(sv);
            accs += v ? sv : 0.f;
        }
        // remainder chunks: pipelined re-gather of tails/A4 -> te
        if (NJ == 4) {
            for (int base = r0 + 16; base < r1; base += 16) {
                int tj[4]; float aj[4]; uint2 vj[4];
#pragma unroll
                for (int j = 0; j < 4; ++j) {
                    int i = base + q + 4 * j;
                    bool v = (i < r1);
                    int ic = v ? i : 0;
                    tj[j] = csr_tail[ic];
                    if (!(FLAGS & FL_ACONST)) aj[j] = A4[ic * 4 + f];
                }
#pragma unroll
                for (int j = 0; j < 4; ++j)
                    vj[j] = *(const uint2*)(te + tj[j] * 64 + 4 * l);
#pragma unroll
                for (int j = 0; j < 4; ++j) {
                    int i = base + q + 4 * j;
                    bool v = (i < r1);
                    float dot = dot2bf(vj[j].y, p23, dot2bf(vj[j].x, p01, 0.0f));
                    dot += __shfl_xor(dot, 1); dot += __shfl_xor(dot, 2);
                    float a = (FLAGS & FL_ACONST) ? 1.0f : aj[j];
                    a += dot;
                    if ((FLAGS & FL_ASTORE) && v && (l & 3) == 0)
                        A4[i * 4 + f] = a;
                    float ex = __expf(a);
                    float sum = ex;
                    sum += __shfl_xor(sum, 4); sum += __shfl_xor(sum, 8);
                    float sv = ex / sum;
                    if (v && (l & 3) == 0)
                        svals[i * 4 + f] = f2bf(sv);
                    accs += v ? sv : 0.f;
                }
            }
        }
        // reduce over edge slots q (value replicated over the l&3 dups)
        accs += __shfl_xor(accs, 16); accs += __shfl_xor(accs, 32);
        if (lane < 16 && (l & 3) == 0) {
            float d = (accs > 0.f) ? 1.0f / sqrtf(fmaxf(accs, 1e-12f)) : 0.f;
            d4n[n * 4 + f] = d;
        }
    }
}

// dispatcher: one wave per node; deg is wave-uniform (SGPR) -> scalar branch
template<int FLAGS>
__global__ void k_iter(unsigned short* __restrict__ svals,
                       const float* __restrict__ d4c,
                       const unsigned short* __restrict__ ego,
                       const unsigned short* __restrict__ te,
                       const int* __restrict__ row_start, const int* __restrict__ csr_tail,
                       float* __restrict__ A4,
                       float* __restrict__ d4n,
                       float* __restrict__ out,
                       unsigned short* __restrict__ egon, unsigned short* __restrict__ ten) {
    int n = (blockIdx.x * 256 + threadIdx.x) >> 6;
    if (n >= NN) return;
    int lane = threadIdx.x & 63;
    int q = lane >> 4;
    int l = lane & 15;
    int f = l >> 2;
    int r0 = __builtin_amdgcn_readfirstlane(row_start[n]);
    int r1 = __builtin_amdgcn_readfirstlane(row_start[n + 1]);
    int deg = r1 - r0;
    if (deg <= 8) {
        if (deg <= 4)
            iter_body<FLAGS, 1>(n, lane, q, l, f, r0, r1, svals, d4c, ego, te,
                                csr_tail, A4, d4n, out, egon, ten);
        else
            iter_body<FLAGS, 2>(n, lane, q, l, f, r0, r1, svals, d4c, ego, te,
                                csr_tail, A4, d4n, out, egon, ten);
    } else {
        if (deg <= 12)
            iter_body<FLAGS, 3>(n, lane, q, l, f, r0, r1, svals, d4c, ego, te,
                                csr_tail, A4, d4n, out, egon, ten);
        else
            iter_body<FLAGS, 4>(n, lane, q, l, f, r0, r1, svals, d4c, ego, te,
                                csr_tail, A4, d4n, out, egon, ten);
    }
}

extern "C" void kernel_launch(void* const* d_in, const int* in_sizes, int n_in,
                              void* d_out, int out_size, void* d_ws, size_t ws_size,
                              hipStream_t stream) {
    const float* eu = (const float*)d_in[0];
    const float* ei = (const float*)d_in[1];
    const int* head = (const int*)d_in[2];
    const int* tail = (const int*)d_in[3];
    float* out = (float*)d_out;   // holds init until it3's 3-term mean (FL_FIN)

    // workspace layout — ~87 MB (16B-aligned first).
    // bin (8 MB, CSR-build scratch) aliases A4's first half: bin is dead after
    // k_bucket; A4 is first written in it0 (same stream => ordered).
    float* A4 = (float*)d_ws;                               // 16 MB
    float* d4a = A4 + (size_t)NNZ_ * 4;                     // 1.6 MB
    float* d4b = d4a + (size_t)NN * 4;                      // 1.6 MB
    unsigned short* svals = (unsigned short*)(d4b + (size_t)NN * 4);  // 8 MB
    unsigned short* ego_a = svals + (size_t)NNZ_ * 4;       // 12.8 MB
    unsigned short* te_a  = ego_a + (size_t)NN * DIM_;      // 12.8 MB
    unsigned short* ego_b = te_a + (size_t)NN * DIM_;       // 12.8 MB
    unsigned short* te_b  = ego_b + (size_t)NN * DIM_;      // 12.8 MB
    int* csr_tail = (int*)(te_b + (size_t)NN * DIM_);       // 4 MB
    int* row_start = csr_tail + NNZ_;                       // NN+1
    int* bcount = row_start + (NN + 1);                     // NBLK
    int* bucket_base = bcount + NBLK;                       // NBLK+1
    int* bucket_cursor = bucket_base + (NBLK + 1);          // NBLK
    int2* bin = (int2*)A4;                                  // 8 MB alias

    const int node_blocks = ceil_div(NN * DIM_, 256);      // 25000
    const int wave_blocks = ceil_div(NN * 64, 256);        // 25000
    const int edge_pass_blocks = ceil_div(NNZ_, EPB);      // 782

    k_init<<<node_blocks, 256, 0, stream>>>(eu, ei, ego_a, te_a, out);

    // bucketed CSR build + d4_0 seed (d = 2/sqrt(deg) since svals_0 = 0.25)
    hipMemsetAsync(bcount, 0, NBLK * sizeof(int), stream);
    k_bcount<<<edge_pass_blocks, 256, 0, stream>>>(head, bcount);
    k_bscan<<<1, 512, 0, stream>>>(bcount, bucket_base, bucket_cursor, &row_start[NN]);
    k_binscat<<<edge_pass_blocks, 256, 0, stream>>>(head, tail, bucket_cursor, bin);
    k_bucket<<<NBLK, 256, 0, stream>>>(bin, bucket_base, row_start, (float4*)d4a, csr_tail);

    // it0 = (0,0): gather with svals==0.25; scores vs te_a: A1 = 1 + s0 (store),
    // svals_1 = softmax(A1), d4b = D(svals_1).
    k_iter<FL_SVC | FL_SC | FL_ACONST | FL_ASTORE><<<wave_blocks, 256, 0, stream>>>(
        svals, d4a, ego_a, te_a, row_start, csr_tail, A4, d4b, out, ego_b, te_b);

    // it1 = (0,1): layer-0 output -> ego_b/te_b (FL_NEXT); scores vs te_a:
    // A2 = A1 + s1 (store), svals_2, d4a.
    k_iter<FL_SC | FL_ASTORE | FL_NEXT><<<wave_blocks, 256, 0, stream>>>(
        svals, d4b, ego_a, te_a, row_start, csr_tail, A4, d4a, out, ego_b, te_b);

    // it2 = (1,0): gather ego_b; scores vs te_b: A3 = A2 + s2 (A3 store dead),
    // svals_3, d4b. No fn store needed at all.
    k_iter<FL_SC><<<wave_blocks, 256, 0, stream>>>(
        svals, d4a, ego_b, te_b, row_start, csr_tail, A4, d4b, out, ego_b, te_b);

    // it3 = (1,1): no scores; final out = (init + fn1(bf16 via ego_b) + fn3) / 3.
    k_iter<FL_FIN><<<wave_blocks, 256, 0, stream>>>(
        svals, d4b, ego_b, te_b, row_start, csr_tail, A4, d4a, out, ego_b, te_b);
}

// Round 7
// 350.649 us; speedup vs baseline: 1.0884x; 1.0884x over previous
//
#include <hip/hip_runtime.h>
#include <hip/hip_bf16.h>

// DGCF forward, MI355X. f32 in/out.
// R11: bucketed CSR build. R12: all-lane epilogue. R13: fused scores.
// R14: software-pipelined chunks. R15 (reverted): f32 tables.
// R16: deg-adaptive chunk depth + 32-bit indices. R17: dot2bf (kept),
// EPB=1280 (reverted — doubled bucket-atomic volume).
// R18: pre-scaled gather tables G[n] = x[n]*d[n,f], rebuilt in-wave in the
// epilogue (d = rsqrt(accs) is already wave-resident after scores) -> the
// per-edge d4c gather, its addr math and the weight mul disappear from the
// walk; d4n table dies; it0's uniform 0.25 weight cancels in the l2norm.
// Scores A4+svals stores merged under one exec-mask toggle.
#define NUSER 50000
#define NITEM 50000
#define NN    100000          // NUSER+NITEM
#define NNZ_  1000000
#define DIM_  64
#define NBLK  391             // ceil_div(NN,256) == bucket count
#define EPB   2560            // edges per count/scatter block (391*2560 >= NNZ)

#define FL_SVC    1   // walk weights uniform (it0; constant cancels in norm)
#define FL_SC     2   // fused scores: dot(fn, te[tail]) -> A -> softmax -> svals
#define FL_NEXT   8   // write ego_next(raw) / te_next / Gnext(from regs)
#define FL_FIN    16  // out = (out + X_row + fn) / 3
#define FL_ACONST 32  // scores: A_old == 1
#define FL_ASTORE 64  // scores: store A_new
#define FL_GN     128 // build Gnext = X_row * d  (X loaded, d from scores)

static inline int ceil_div(int a, int b) { return (a + b - 1) / b; }

static __device__ inline float bf2f(unsigned short u) {
    return __uint_as_float(((unsigned int)u) << 16);
}
static __device__ inline unsigned short f2bf(float f) {
    unsigned int x = __float_as_uint(f);
    x += 0x7fffu + ((x >> 16) & 1u);
    return (unsigned short)(x >> 16);
}

// packed bf16x2 dot: c += a.lo*b.lo + a.hi*b.hi (hw v_dot2_f32_bf16 if present)
#if __has_builtin(__builtin_amdgcn_fdot2_f32_bf16)
typedef __bf16 bf16x2_t __attribute__((ext_vector_type(2)));
static __device__ inline float dot2bf(unsigned int a, unsigned int b, float c) {
    return __builtin_amdgcn_fdot2_f32_bf16(__builtin_bit_cast(bf16x2_t, a),
                                           __builtin_bit_cast(bf16x2_t, b), c, false);
}
#else
static __device__ inline float dot2bf(unsigned int a, unsigned int b, float c) {
    return c + bf2f((unsigned short)(a & 0xffffu)) * bf2f((unsigned short)(b & 0xffffu))
             + bf2f((unsigned short)(a >> 16)) * bf2f((unsigned short)(b >> 16));
}
#endif

// ---- bucketed CSR build (once per launch) ----
__global__ void k_bcount(const int* __restrict__ head, int* __restrict__ bcount) {
    __shared__ int cnt[NBLK];
    int tid = threadIdx.x;
    for (int i = tid; i < NBLK; i += 256) cnt[i] = 0;
    __syncthreads();
    int e0 = blockIdx.x * EPB;
    int e1 = min(e0 + EPB, NNZ_);
    for (int e = e0 + tid; e < e1; e += 256)
        atomicAdd(&cnt[head[e] >> 8], 1);
    __syncthreads();
    for (int i = tid; i < NBLK; i += 256)
        if (cnt[i]) atomicAdd(&bcount[i], cnt[i]);
}

__global__ void k_bscan(const int* __restrict__ bcount, int* __restrict__ bucket_base,
                        int* __restrict__ bucket_cursor, int* __restrict__ row_start_end) {
    __shared__ int sh[512];
    int t = threadIdx.x;
    int v = (t < NBLK) ? bcount[t] : 0;
    sh[t] = v;
    __syncthreads();
    for (int off = 1; off < 512; off <<= 1) {
        int u = 0;
        if (t >= off) u = sh[t - off];
        __syncthreads();
        sh[t] += u;
        __syncthreads();
    }
    if (t < NBLK) {
        int base = sh[t] - v;
        bucket_base[t] = base;
        bucket_cursor[t] = base;
    }
    if (t == 511) {
        bucket_base[NBLK] = sh[511];    // == NNZ_
        row_start_end[0] = sh[511];
    }
}

__global__ void k_binscat(const int* __restrict__ head, const int* __restrict__ tail,
                          int* __restrict__ bucket_cursor, int2* __restrict__ bin) {
    __shared__ int cnt[NBLK];
    __shared__ int chunk[NBLK];
    int tid = threadIdx.x;
    for (int i = tid; i < NBLK; i += 256) cnt[i] = 0;
    __syncthreads();
    int e0 = blockIdx.x * EPB;
    int e1 = min(e0 + EPB, NNZ_);
    for (int e = e0 + tid; e < e1; e += 256)
        atomicAdd(&cnt[head[e] >> 8], 1);
    __syncthreads();
    for (int i = tid; i < NBLK; i += 256) {
        chunk[i] = cnt[i] ? atomicAdd(&bucket_cursor[i], cnt[i]) : 0;
        cnt[i] = 0;   // reuse as local cursor
    }
    __syncthreads();
    for (int e = e0 + tid; e < e1; e += 256) {
        int h = head[e], t = tail[e];
        int b = h >> 8;
        int off = atomicAdd(&cnt[b], 1);
        bin[chunk[b] + off] = make_int2(h, t);
    }
}

__global__ void k_bucket(const int2* __restrict__ bin, const int* __restrict__ bucket_base,
                         int* __restrict__ row_start, float4* __restrict__ d4a,
                         int* __restrict__ csr_tail) {
    __shared__ int deg[256];
    __shared__ int sh[256];
    __shared__ int cur[256];
    int tid = threadIdx.x;
    int b = blockIdx.x;
    int n0 = b << 8;
    int e0 = bucket_base[b], e1 = bucket_base[b + 1];
    deg[tid] = 0;
    __syncthreads();
    for (int e = e0 + tid; e < e1; e += 256)
        atomicAdd(&deg[bin[e].x - n0], 1);
    __syncthreads();
    int myDeg = deg[tid];
    sh[tid] = myDeg;
    __syncthreads();
    for (int off = 1; off < 256; off <<= 1) {
        int u = 0;
        if (tid >= off) u = sh[tid - off];
        __syncthreads();
        sh[tid] += u;
        __syncthreads();
    }
    int loff = sh[tid] - myDeg;   // exclusive local offset
    int n = n0 + tid;
    if (n < NN) {
        row_start[n] = e0 + loff;
        float dd = (myDeg > 0) ? 2.0f / sqrtf((float)myDeg) : 0.0f;
        d4a[n] = make_float4(dd, dd, dd, dd);
    }
    cur[tid] = e0 + loff;
    __syncthreads();
    for (int e = e0 + tid; e < e1; e += 256) {
        int2 p = bin[e];
        int pos = atomicAdd(&cur[p.x - n0], 1);
        csr_tail[pos] = p.y;
    }
}

// ego = raw bf16; te = tanh(l2norm chunk16); G0 = ego*d0; out = ego f32.
// Runs AFTER the CSR build (reads d4a for the G0 seed).
__global__ void k_init(const float* __restrict__ eu, const float* __restrict__ ei,
                       const float* __restrict__ d4a,   // viewed as float[NN*4]
                       unsigned short* __restrict__ ego, unsigned short* __restrict__ te,
                       unsigned short* __restrict__ G0, float* __restrict__ out) {
    int i = blockIdx.x * 256 + threadIdx.x;
    if (i >= NN * DIM_) return;
    float v = (i < NUSER * DIM_) ? eu[i] : ei[i - NUSER * DIM_];
    out[i] = v;
    ego[i] = f2bf(v);
    G0[i] = f2bf(v * d4a[i >> 4]);   // i>>4 == n*4 + f
    float s = v * v;
    s += __shfl_xor(s, 1); s += __shfl_xor(s, 2);
    s += __shfl_xor(s, 4); s += __shfl_xor(s, 8);
    float nrm = v / fmaxf(sqrtf(s), 1e-12f);
    float ex = __expf(2.0f * nrm);
    te[i] = f2bf((ex - 1.0f) / (ex + 1.0f));
}

// ---- fused walk + scores body, NJ = chunk depth in 4-edge steps ----
// lane = 16*q + l: q = edge slot (0..3), l = dim quad (dims 4l..4l+3), f = l>>2.
// Walk gathers the PRE-SCALED table G (w = sval only; it0 w = 1).
// Epilogue rebuilds Gnext = X*d (or fn*d for FL_NEXT) with this wave's d.
template<int FLAGS, int NJ>
static __device__ __forceinline__ void iter_body(
    int n, int lane, int q, int l, int f, int r0, int r1,
    unsigned short* __restrict__ svals,
    const unsigned short* __restrict__ G,
    const unsigned short* __restrict__ te,
    const int* __restrict__ csr_tail,
    float* __restrict__ A4,
    float* __restrict__ out,
    const unsigned short* __restrict__ X,   // raw row source (GN / FIN)
    unsigned short* __restrict__ Gn,
    unsigned short* __restrict__ egon, unsigned short* __restrict__ ten)
{
    float ax = 0.f, ay = 0.f, az = 0.f, aw = 0.f;

    // ---- chunk 0: edges r0+q+4j, j=0..NJ-1 (te cached for scores phase) ----
    int ct[NJ]; float cw[NJ]; float ca[NJ]; uint2 cv[NJ];
    int eb = r0 + q;
#pragma unroll
    for (int j = 0; j < NJ; ++j) {
        int i = eb + 4 * j;
        bool v = (i < r1);
        int ic = v ? i : 0;
        ct[j] = csr_tail[ic];
        float w;
        if (FLAGS & FL_SVC) w = 1.0f;
        else w = bf2f(svals[ic * 4 + f]);
        cw[j] = v ? w : 0.f;
        if ((FLAGS & FL_SC) && !(FLAGS & FL_ACONST))
            ca[j] = A4[ic * 4 + f];
    }
#pragma unroll
    for (int j = 0; j < NJ; ++j) {
        if (FLAGS & FL_SC)
            cv[j] = *(const uint2*)(te + ct[j] * 64 + 4 * l);
    }
#pragma unroll
    for (int j = 0; j < NJ; ++j) {
        ushort4 u = *(const ushort4*)(G + ct[j] * 64 + 4 * l);
        ax += cw[j] * bf2f(u.x); ay += cw[j] * bf2f(u.y);
        az += cw[j] * bf2f(u.z); aw += cw[j] * bf2f(u.w);
    }

    // ---- remainder chunks (deg > 16), only reachable in the NJ==4 arm ----
    if (NJ == 4) {
        for (int base = r0 + 16; base < r1; base += 16) {
            int tj[4]; float wj[4];
#pragma unroll
            for (int j = 0; j < 4; ++j) {
                int i = base + q + 4 * j;
                bool v = (i < r1);
                int ic = v ? i : 0;
                tj[j] = csr_tail[ic];
                float w;
                if (FLAGS & FL_SVC) w = 1.0f;
                else w = bf2f(svals[ic * 4 + f]);
                wj[j] = v ? w : 0.f;
            }
#pragma unroll
            for (int j = 0; j < 4; ++j) {
                ushort4 u = *(const ushort4*)(G + tj[j] * 64 + 4 * l);
                ax += wj[j] * bf2f(u.x); ay += wj[j] * bf2f(u.y);
                az += wj[j] * bf2f(u.z); aw += wj[j] * bf2f(u.w);
            }
        }
    }

    // reduce over edge slots -> each lane holds full sums for its dim quad
    ax += __shfl_xor(ax, 16); ax += __shfl_xor(ax, 32);
    ay += __shfl_xor(ay, 16); ay += __shfl_xor(ay, 32);
    az += __shfl_xor(az, 16); az += __shfl_xor(az, 32);
    aw += __shfl_xor(aw, 16); aw += __shfl_xor(aw, 32);

    // l2 norm over the 16-dim factor chunk (quad layout: reduce over l&3)
    float s = ax * ax + ay * ay + az * az + aw * aw;
    s += __shfl_xor(s, 1); s += __shfl_xor(s, 2);
    float inv = 1.0f / fmaxf(sqrtf(s), 1e-12f);
    float fx = ax * inv, fy = ay * inv, fz = az * inv, fw = aw * inv;

    float y = 0.f;
    if (FLAGS & (FL_NEXT | FL_FIN)) {
        // redistribute: lane p takes dim p (= component p&3 of lane p>>2's quad)
        int src = lane >> 2;
        float t0r = __shfl(fx, src), t1r = __shfl(fy, src);
        float t2r = __shfl(fz, src), t3r = __shfl(fw, src);
        y = (lane & 2) ? ((lane & 1) ? t3r : t2r) : ((lane & 1) ? t1r : t0r);
        int base = n * 64 + lane;
        if (FLAGS & FL_FIN) {
            // out holds init; X row n holds bf16 fn1 -> 3-term mean
            out[base] = (out[base] + bf2f(X[base]) + y) * (1.0f / 3.0f);
        }
        if (FLAGS & FL_NEXT) {
            egon[base] = f2bf(y);
            float e2 = __expf(2.0f * y);
            ten[base] = f2bf((e2 - 1.0f) / (e2 + 1.0f));
        }
    }

    float accs = 0.f;   // rowsum of svals for this lane's factor f
    if (FLAGS & FL_SC) {
        // pack fn once per node: lane's 4 dims -> two bf16x2 dwords
        unsigned int p01 = ((unsigned int)f2bf(fy) << 16) | f2bf(fx);
        unsigned int p23 = ((unsigned int)f2bf(fw) << 16) | f2bf(fz);
        // cached chunk 0: pure register compute
#pragma unroll
        for (int j = 0; j < NJ; ++j) {
            int i = eb + 4 * j;
            bool v = (i < r1);
            float dot = dot2bf(cv[j].y, p23, dot2bf(cv[j].x, p01, 0.0f));
            dot += __shfl_xor(dot, 1); dot += __shfl_xor(dot, 2);
            float a = (FLAGS & FL_ACONST) ? 1.0f : ca[j];
            a += dot;
            float ex = __expf(a);
            float sum = ex;
            sum += __shfl_xor(sum, 4); sum += __shfl_xor(sum, 8);
            float sv = ex / sum;
            if (v && (l & 3) == 0) {      // one exec-mask region for both stores
                if (FLAGS & FL_ASTORE) A4[i * 4 + f] = a;
                svals[i * 4 + f] = f2bf(sv);
            }
            accs += v ? sv : 0.f;
        }
        // remainder chunks: pipelined re-gather of tails/A4 -> te
        if (NJ == 4) {
            for (int base = r0 + 16; base < r1; base += 16) {
                int tj[4]; float aj[4]; uint2 vj[4];
#pragma unroll
                for (int j = 0; j < 4; ++j) {
                    int i = base + q + 4 * j;
                    bool v = (i < r1);
                    int ic = v ? i : 0;
                    tj[j] = csr_tail[ic];
                    if (!(FLAGS & FL_ACONST)) aj[j] = A4[ic * 4 + f];
                }
#pragma unroll
                for (int j = 0; j < 4; ++j)
                    vj[j] = *(const uint2*)(te + tj[j] * 64 + 4 * l);
#pragma unroll
                for (int j = 0; j < 4; ++j) {
                    int i = base + q + 4 * j;
                    bool v = (i < r1);
                    float dot = dot2bf(vj[j].y, p23, dot2bf(vj[j].x, p01, 0.0f));
                    dot += __shfl_xor(dot, 1); dot += __shfl_xor(dot, 2);
                    float a = (FLAGS & FL_ACONST) ? 1.0f : aj[j];
                    a += dot;
                    float ex = __expf(a);
                    float sum = ex;
                    sum += __shfl_xor(sum, 4); sum += __shfl_xor(sum, 8);
                    float sv = ex / sum;
                    if (v && (l & 3) == 0) {
                        if (FLAGS & FL_ASTORE) A4[i * 4 + f] = a;
                        svals[i * 4 + f] = f2bf(sv);
                    }
                    accs += v ? sv : 0.f;
                }
            }
        }
        // reduce over edge slots q (value replicated over the l&3 dups)
        accs += __shfl_xor(accs, 16); accs += __shfl_xor(accs, 32);
    }

    if (FLAGS & (FL_GN | FL_NEXT)) {
        // d for this lane's OUTPUT factor (dim = lane, factor = lane>>4):
        // accs for factor g lives on lane 4*g (and dups).
        float av = __shfl(accs, (lane >> 4) << 2);
        float d = (av > 0.f) ? 1.0f / sqrtf(fmaxf(av, 1e-12f)) : 0.f;
        int base = n * 64 + lane;
        float src = (FLAGS & FL_NEXT) ? y : bf2f(X[base]);
        Gn[base] = f2bf(src * d);
    }
}

// dispatcher: one wave per node; deg is wave-uniform (SGPR) -> scalar branch
template<int FLAGS>
__global__ void k_iter(unsigned short* __restrict__ svals,
                       const unsigned short* __restrict__ G,
                       const unsigned short* __restrict__ te,
                       const int* __restrict__ row_start, const int* __restrict__ csr_tail,
                       float* __restrict__ A4,
                       float* __restrict__ out,
                       const unsigned short* __restrict__ X,
                       unsigned short* __restrict__ Gn,
                       unsigned short* __restrict__ egon, unsigned short* __restrict__ ten) {
    int n = (blockIdx.x * 256 + threadIdx.x) >> 6;
    if (n >= NN) return;
    int lane = threadIdx.x & 63;
    int q = lane >> 4;
    int l = lane & 15;
    int f = l >> 2;
    int r0 = __builtin_amdgcn_readfirstlane(row_start[n]);
    int r1 = __builtin_amdgcn_readfirstlane(row_start[n + 1]);
    int deg = r1 - r0;
    if (deg <= 8) {
        if (deg <= 4)
            iter_body<FLAGS, 1>(n, lane, q, l, f, r0, r1, svals, G, te,
                                csr_tail, A4, out, X, Gn, egon, ten);
        else
            iter_body<FLAGS, 2>(n, lane, q, l, f, r0, r1, svals, G, te,
                                csr_tail, A4, out, X, Gn, egon, ten);
    } else {
        if (deg <= 12)
            iter_body<FLAGS, 3>(n, lane, q, l, f, r0, r1, svals, G, te,
                                csr_tail, A4, out, X, Gn, egon, ten);
        else
            iter_body<FLAGS, 4>(n, lane, q, l, f, r0, r1, svals, G, te,
                                csr_tail, A4, out, X, Gn, egon, ten);
    }
}

extern "C" void kernel_launch(void* const* d_in, const int* in_sizes, int n_in,
                              void* d_out, int out_size, void* d_ws, size_t ws_size,
                              hipStream_t stream) {
    const float* eu = (const float*)d_in[0];
    const float* ei = (const float*)d_in[1];
    const int* head = (const int*)d_in[2];
    const int* tail = (const int*)d_in[3];
    float* out = (float*)d_out;   // holds init until it3's 3-term mean (FL_FIN)

    // workspace layout — ~107 MB (16B-aligned first).
    // bin (8 MB, CSR-build scratch) aliases A4 (dead before A4's first write).
    float* A4 = (float*)d_ws;                               // 16 MB
    float* d4a = A4 + (size_t)NNZ_ * 4;                     // 1.6 MB (it0 seed only)
    unsigned short* svals = (unsigned short*)(d4a + (size_t)NN * 4);  // 8 MB
    unsigned short* ego_a = svals + (size_t)NNZ_ * 4;       // 12.8 MB (raw)
    unsigned short* te_a  = ego_a + (size_t)NN * DIM_;      // 12.8 MB
    unsigned short* ego_b = te_a + (size_t)NN * DIM_;       // 12.8 MB (raw fn1)
    unsigned short* te_b  = ego_b + (size_t)NN * DIM_;      // 12.8 MB
    unsigned short* Ga    = te_b + (size_t)NN * DIM_;       // 12.8 MB
    unsigned short* Gb    = Ga + (size_t)NN * DIM_;         // 12.8 MB
    int* csr_tail = (int*)(Gb + (size_t)NN * DIM_);         // 4 MB
    int* row_start = csr_tail + NNZ_;                       // NN+1
    int* bcount = row_start + (NN + 1);                     // NBLK
    int* bucket_base = bcount + NBLK;                       // NBLK+1
    int* bucket_cursor = bucket_base + (NBLK + 1);          // NBLK
    int2* bin = (int2*)A4;                                  // 8 MB alias

    const int node_blocks = ceil_div(NN * DIM_, 256);      // 25000
    const int wave_blocks = ceil_div(NN * 64, 256);        // 25000

    // bucketed CSR build + d0 = 2/sqrt(deg) seed (rowsum0 = 0.25*deg)
    hipMemsetAsync(bcount, 0, NBLK * sizeof(int), stream);
    k_bcount<<<NBLK, 256, 0, stream>>>(head, bcount);
    k_bscan<<<1, 512, 0, stream>>>(bcount, bucket_base, bucket_cursor, &row_start[NN]);
    k_binscat<<<NBLK, 256, 0, stream>>>(head, tail, bucket_cursor, bin);
    k_bucket<<<NBLK, 256, 0, stream>>>(bin, bucket_base, row_start, (float4*)d4a, csr_tail);

    // init AFTER csr build: ego_a raw, te_a, G0 = ego_a*d0 -> Ga, out = init
    k_init<<<node_blocks, 256, 0, stream>>>(eu, ei, d4a, ego_a, te_a, Ga, out);

    // it0: walk Ga (uniform weights cancel in norm); scores vs te_a:
    // A1 = 1 + s0 (store), svals_1; epilogue G1 = ego_a*d1 -> Gb.
    k_iter<FL_SVC | FL_SC | FL_ACONST | FL_ASTORE | FL_GN><<<wave_blocks, 256, 0, stream>>>(
        svals, Ga, te_a, row_start, csr_tail, A4, out, ego_a, Gb, ego_b, te_b);

    // it1: walk Gb with svals_1; fn1 -> ego_b(raw) + te_b; scores vs te_a:
    // A2 = A1 + s1 (store), svals_2; epilogue G2 = fn1*d2 -> Ga.
    k_iter<FL_SC | FL_ASTORE | FL_NEXT><<<wave_blocks, 256, 0, stream>>>(
        svals, Gb, te_a, row_start, csr_tail, A4, out, ego_a, Ga, ego_b, te_b);

    // it2: walk Ga with svals_2; scores vs te_b: A3 = A2 + s2 (store dead),
    // svals_3; epilogue G3 = ego_b*d3 -> Gb.
    k_iter<FL_SC | FL_GN><<<wave_blocks, 256, 0, stream>>>(
        svals, Ga, te_b, row_start, csr_tail, A4, out, ego_b, Gb, ego_b, te_b);

    // it3: walk Gb with svals_3; no scores; out = (init + fn1 + fn3)/3.
    k_iter<FL_FIN><<<wave_blocks, 256, 0, stream>>>(
        svals, Gb, te_b, row_start, csr_tail, A4, out, ego_b, Ga, ego_b, te_b);
}

// Round 9
// 342.054 us; speedup vs baseline: 1.1158x; 1.0251x over previous
//
#include <hip/hip_runtime.h>
#include <hip/hip_bf16.h>

// DGCF forward, MI355X. f32 in/out.
// R11: bucketed CSR build. R12: all-lane epilogue. R13: fused scores.
// R14: software-pipelined chunks. R16: deg-adaptive chunk depth + 32-bit idx.
// R17: dot2bf. R18: pre-scaled gather tables G = x*d rebuilt in-wave.
// R19 (bug): padded-bucket CSR killed k_bcount/k_bscan but svals/A4 were
// still sized for 1M edges while CSR positions span NBLK*BINC=1.6M -> OOB
// writes corrupted ego/te (NaN).
// R20: fix — svals/A4/csr_tail sized NPAD = NBLK*BINC; invalid-lane tail
// loads select-0 after load (deg-0 rows' padding holes are uninitialized).
#define NUSER 50000
#define NITEM 50000
#define NN    100000          // NUSER+NITEM
#define NNZ_  1000000
#define DIM_  64
#define NBLK  391             // ceil_div(NN,256) == bucket count
#define EPB   2560            // edges per scatter block (391*2560 >= NNZ)
#define BINC  4096            // per-bucket window capacity (mean 2560, +30 sigma)
#define NPAD  (NBLK * BINC)   // padded edge-index space (1,601,536)

#define FL_SVC    1   // walk weights uniform (it0; constant cancels in norm)
#define FL_SC     2   // fused scores: dot(fn, te[tail]) -> A -> softmax -> svals
#define FL_NEXT   8   // write ego_next(raw) / te_next / Gnext(from regs)
#define FL_FIN    16  // out = (out + X_row + fn) / 3
#define FL_ACONST 32  // scores: A_old == 1
#define FL_ASTORE 64  // scores: store A_new
#define FL_GN     128 // build Gnext = X_row * d  (X loaded, d from scores)

static inline int ceil_div(int a, int b) { return (a + b - 1) / b; }

static __device__ inline float bf2f(unsigned short u) {
    return __uint_as_float(((unsigned int)u) << 16);
}
static __device__ inline unsigned short f2bf(float f) {
    unsigned int x = __float_as_uint(f);
    x += 0x7fffu + ((x >> 16) & 1u);
    return (unsigned short)(x >> 16);
}

// packed bf16x2 dot: c += a.lo*b.lo + a.hi*b.hi (hw v_dot2_f32_bf16 if present)
#if __has_builtin(__builtin_amdgcn_fdot2_f32_bf16)
typedef __bf16 bf16x2_t __attribute__((ext_vector_type(2)));
static __device__ inline float dot2bf(unsigned int a, unsigned int b, float c) {
    return __builtin_amdgcn_fdot2_f32_bf16(__builtin_bit_cast(bf16x2_t, a),
                                           __builtin_bit_cast(bf16x2_t, b), c, false);
}
#else
static __device__ inline float dot2bf(unsigned int a, unsigned int b, float c) {
    return c + bf2f((unsigned short)(a & 0xffffu)) * bf2f((unsigned short)(b & 0xffffu))
             + bf2f((unsigned short)(a >> 16)) * bf2f((unsigned short)(b >> 16));
}
#endif

// ---- padded-bucket CSR build (once per launch) ----
// scatter (packed) edges into per-bucket fixed windows; cursor = final counts
__global__ void k_binscat(const int* __restrict__ head, const int* __restrict__ tail,
                          int* __restrict__ cursor, int* __restrict__ bin) {
    __shared__ int cnt[NBLK];
    __shared__ int chunk[NBLK];
    int tid = threadIdx.x;
    for (int i = tid; i < NBLK; i += 256) cnt[i] = 0;
    __syncthreads();
    int e0 = blockIdx.x * EPB;
    int e1 = min(e0 + EPB, NNZ_);
    for (int e = e0 + tid; e < e1; e += 256)
        atomicAdd(&cnt[head[e] >> 8], 1);
    __syncthreads();
    for (int i = tid; i < NBLK; i += 256) {
        chunk[i] = cnt[i] ? (i * BINC + atomicAdd(&cursor[i], cnt[i])) : 0;
        cnt[i] = 0;   // reuse as local cursor
    }
    __syncthreads();
    for (int e = e0 + tid; e < e1; e += 256) {
        int h = head[e], t = tail[e];
        int b = h >> 8;
        int off = atomicAdd(&cnt[b], 1);
        bin[chunk[b] + off] = t | ((h & 255) << 20);   // t < 2^17, hl < 2^8
    }
}

// per-bucket: LDS deg hist -> scan -> row_se {start,end} + d4a seed;
// tail scatter via LDS cursors into the bucket's fixed csr window.
__global__ void k_bucket(const int* __restrict__ bin, const int* __restrict__ cursor,
                         int2* __restrict__ row_se, float4* __restrict__ d4a,
                         int* __restrict__ csr_tail) {
    __shared__ int deg[256];
    __shared__ int sh[256];
    __shared__ int cur[256];
    int tid = threadIdx.x;
    int b = blockIdx.x;
    int n0 = b << 8;
    int e0 = b * BINC, e1 = e0 + cursor[b];
    deg[tid] = 0;
    __syncthreads();
    for (int e = e0 + tid; e < e1; e += 256)
        atomicAdd(&deg[bin[e] >> 20], 1);
    __syncthreads();
    int myDeg = deg[tid];
    sh[tid] = myDeg;
    __syncthreads();
    for (int off = 1; off < 256; off <<= 1) {
        int u = 0;
        if (tid >= off) u = sh[tid - off];
        __syncthreads();
        sh[tid] += u;
        __syncthreads();
    }
    int loff = sh[tid] - myDeg;   // exclusive local offset
    int start = b * BINC + loff;  // csr window shares the BINC stride
    int n = n0 + tid;
    if (n < NN) {
        row_se[n] = make_int2(start, start + myDeg);
        float dd = (myDeg > 0) ? 2.0f / sqrtf((float)myDeg) : 0.0f;
        d4a[n] = make_float4(dd, dd, dd, dd);
    }
    cur[tid] = start;
    __syncthreads();
    for (int e = e0 + tid; e < e1; e += 256) {
        int p = bin[e];
        int pos = atomicAdd(&cur[p >> 20], 1);
        csr_tail[pos] = p & 0xFFFFF;
    }
}

// ego = raw bf16; te = tanh(l2norm chunk16); G0 = ego*d0; out = ego f32.
// Runs AFTER the CSR build (reads d4a for the G0 seed).
__global__ void k_init(const float* __restrict__ eu, const float* __restrict__ ei,
                       const float* __restrict__ d4a,   // viewed as float[NN*4]
                       unsigned short* __restrict__ ego, unsigned short* __restrict__ te,
                       unsigned short* __restrict__ G0, float* __restrict__ out) {
    int i = blockIdx.x * 256 + threadIdx.x;
    if (i >= NN * DIM_) return;
    float v = (i < NUSER * DIM_) ? eu[i] : ei[i - NUSER * DIM_];
    out[i] = v;
    ego[i] = f2bf(v);
    G0[i] = f2bf(v * d4a[i >> 4]);   // i>>4 == n*4 + f
    float s = v * v;
    s += __shfl_xor(s, 1); s += __shfl_xor(s, 2);
    s += __shfl_xor(s, 4); s += __shfl_xor(s, 8);
    float nrm = v / fmaxf(sqrtf(s), 1e-12f);
    float ex = __expf(2.0f * nrm);
    te[i] = f2bf((ex - 1.0f) / (ex + 1.0f));
}

// ---- fused walk + scores body, NJ = chunk depth in 4-edge steps ----
// lane = 16*q + l: q = edge slot (0..3), l = dim quad (dims 4l..4l+3), f = l>>2.
// Walk gathers the PRE-SCALED table G (w = sval only; it0 w = 1).
// Epilogue rebuilds Gnext = X*d (or fn*d for FL_NEXT) with this wave's d.
template<int FLAGS, int NJ>
static __device__ __forceinline__ void iter_body(
    int n, int lane, int q, int l, int f, int r0, int r1,
    unsigned short* __restrict__ svals,
    const unsigned short* __restrict__ G,
    const unsigned short* __restrict__ te,
    const int* __restrict__ csr_tail,
    float* __restrict__ A4,
    float* __restrict__ out,
    const unsigned short* __restrict__ X,   // raw row source (GN / FIN)
    unsigned short* __restrict__ Gn,
    unsigned short* __restrict__ egon, unsigned short* __restrict__ ten)
{
    float ax = 0.f, ay = 0.f, az = 0.f, aw = 0.f;

    // ---- chunk 0: edges r0+q+4j, j=0..NJ-1 (te cached for scores phase) ----
    int ct[NJ]; float cw[NJ]; float ca[NJ]; uint2 cv[NJ];
    int eb = r0 + q;
#pragma unroll
    for (int j = 0; j < NJ; ++j) {
        int i = eb + 4 * j;
        bool v = (i < r1);
        int ic = v ? i : r0;
        int t = csr_tail[ic];
        ct[j] = v ? t : 0;            // padding holes are uninitialized
        float w;
        if (FLAGS & FL_SVC) w = 1.0f;
        else w = bf2f(svals[ic * 4 + f]);
        cw[j] = v ? w : 0.f;
        if ((FLAGS & FL_SC) && !(FLAGS & FL_ACONST))
            ca[j] = A4[ic * 4 + f];
    }
#pragma unroll
    for (int j = 0; j < NJ; ++j) {
        if (FLAGS & FL_SC)
            cv[j] = *(const uint2*)(te + ct[j] * 64 + 4 * l);
    }
#pragma unroll
    for (int j = 0; j < NJ; ++j) {
        ushort4 u = *(const ushort4*)(G + ct[j] * 64 + 4 * l);
        ax += cw[j] * bf2f(u.x); ay += cw[j] * bf2f(u.y);
        az += cw[j] * bf2f(u.z); aw += cw[j] * bf2f(u.w);
    }

    // ---- remainder chunks (deg > 16), only reachable in the NJ==4 arm ----
    if (NJ == 4) {
        for (int base = r0 + 16; base < r1; base += 16) {
            int tj[4]; float wj[4];
#pragma unroll
            for (int j = 0; j < 4; ++j) {
                int i = base + q + 4 * j;
                bool v = (i < r1);
                int ic = v ? i : r0;
                int t = csr_tail[ic];
                tj[j] = v ? t : 0;
                float w;
                if (FLAGS & FL_SVC) w = 1.0f;
                else w = bf2f(svals[ic * 4 + f]);
                wj[j] = v ? w : 0.f;
            }
#pragma unroll
            for (int j = 0; j < 4; ++j) {
                ushort4 u = *(const ushort4*)(G + tj[j] * 64 + 4 * l);
                ax += wj[j] * bf2f(u.x); ay += wj[j] * bf2f(u.y);
                az += wj[j] * bf2f(u.z); aw += wj[j] * bf2f(u.w);
            }
        }
    }

    // reduce over edge slots -> each lane holds full sums for its dim quad
    ax += __shfl_xor(ax, 16); ax += __shfl_xor(ax, 32);
    ay += __shfl_xor(ay, 16); ay += __shfl_xor(ay, 32);
    az += __shfl_xor(az, 16); az += __shfl_xor(az, 32);
    aw += __shfl_xor(aw, 16); aw += __shfl_xor(aw, 32);

    // l2 norm over the 16-dim factor chunk (quad layout: reduce over l&3)
    float s = ax * ax + ay * ay + az * az + aw * aw;
    s += __shfl_xor(s, 1); s += __shfl_xor(s, 2);
    float inv = 1.0f / fmaxf(sqrtf(s), 1e-12f);
    float fx = ax * inv, fy = ay * inv, fz = az * inv, fw = aw * inv;

    float y = 0.f;
    if (FLAGS & (FL_NEXT | FL_FIN)) {
        // redistribute: lane p takes dim p (= component p&3 of lane p>>2's quad)
        int src = lane >> 2;
        float t0r = __shfl(fx, src), t1r = __shfl(fy, src);
        float t2r = __shfl(fz, src), t3r = __shfl(fw, src);
        y = (lane & 2) ? ((lane & 1) ? t3r : t2r) : ((lane & 1) ? t1r : t0r);
        int base = n * 64 + lane;
        if (FLAGS & FL_FIN) {
            // out holds init; X row n holds bf16 fn1 -> 3-term mean
            out[base] = (out[base] + bf2f(X[base]) + y) * (1.0f / 3.0f);
        }
        if (FLAGS & FL_NEXT) {
            egon[base] = f2bf(y);
            float e2 = __expf(2.0f * y);
            ten[base] = f2bf((e2 - 1.0f) / (e2 + 1.0f));
        }
    }

    float accs = 0.f;   // rowsum of svals for this lane's factor f
    if (FLAGS & FL_SC) {
        // pack fn once per node: lane's 4 dims -> two bf16x2 dwords
        unsigned int p01 = ((unsigned int)f2bf(fy) << 16) | f2bf(fx);
        unsigned int p23 = ((unsigned int)f2bf(fw) << 16) | f2bf(fz);
        // cached chunk 0: pure register compute
#pragma unroll
        for (int j = 0; j < NJ; ++j) {
            int i = eb + 4 * j;
            bool v = (i < r1);
            float dot = dot2bf(cv[j].y, p23, dot2bf(cv[j].x, p01, 0.0f));
            dot += __shfl_xor(dot, 1); dot += __shfl_xor(dot, 2);
            float a = (FLAGS & FL_ACONST) ? 1.0f : ca[j];
            a += dot;
            float ex = __expf(a);
            float sum = ex;
            sum += __shfl_xor(sum, 4); sum += __shfl_xor(sum, 8);
            float sv = ex / sum;
            if (v && (l & 3) == 0) {      // one exec-mask region for both stores
                if (FLAGS & FL_ASTORE) A4[i * 4 + f] = a;
                svals[i * 4 + f] = f2bf(sv);
            }
            accs += v ? sv : 0.f;
        }
        // remainder chunks: pipelined re-gather of tails/A4 -> te
        if (NJ == 4) {
            for (int base = r0 + 16; base < r1; base += 16) {
                int tj[4]; float aj[4]; uint2 vj[4];
#pragma unroll
                for (int j = 0; j < 4; ++j) {
                    int i = base + q + 4 * j;
                    bool v = (i < r1);
                    int ic = v ? i : r0;
                    int t = csr_tail[ic];
                    tj[j] = v ? t : 0;
                    if (!(FLAGS & FL_ACONST)) aj[j] = A4[ic * 4 + f];
                }
#pragma unroll
                for (int j = 0; j < 4; ++j)
                    vj[j] = *(const uint2*)(te + tj[j] * 64 + 4 * l);
#pragma unroll
                for (int j = 0; j < 4; ++j) {
                    int i = base + q + 4 * j;
                    bool v = (i < r1);
                    float dot = dot2bf(vj[j].y, p23, dot2bf(vj[j].x, p01, 0.0f));
                    dot += __shfl_xor(dot, 1); dot += __shfl_xor(dot, 2);
                    float a = (FLAGS & FL_ACONST) ? 1.0f : aj[j];
                    a += dot;
                    float ex = __expf(a);
                    float sum = ex;
                    sum += __shfl_xor(sum, 4); sum += __shfl_xor(sum, 8);
                    float sv = ex / sum;
                    if (v && (l & 3) == 0) {
                        if (FLAGS & FL_ASTORE) A4[i * 4 + f] = a;
                        svals[i * 4 + f] = f2bf(sv);
                    }
                    accs += v ? sv : 0.f;
                }
            }
        }
        // reduce over edge slots q (value replicated over the l&3 dups)
        accs += __shfl_xor(accs, 16); accs += __shfl_xor(accs, 32);
    }

    if (FLAGS & (FL_GN | FL_NEXT)) {
        // d for this lane's OUTPUT factor (dim = lane, factor = lane>>4):
        // accs for factor g lives on lane 4*g (and dups).
        float av = __shfl(accs, (lane >> 4) << 2);
        float d = (av > 0.f) ? 1.0f / sqrtf(fmaxf(av, 1e-12f)) : 0.f;
        int base = n * 64 + lane;
        float src = (FLAGS & FL_NEXT) ? y : bf2f(X[base]);
        Gn[base] = f2bf(src * d);
    }
}

// dispatcher: one wave per node; deg is wave-uniform (SGPR) -> scalar branch
template<int FLAGS>
__global__ void k_iter(unsigned short* __restrict__ svals,
                       const unsigned short* __restrict__ G,
                       const unsigned short* __restrict__ te,
                       const int2* __restrict__ row_se, const int* __restrict__ csr_tail,
                       float* __restrict__ A4,
                       float* __restrict__ out,
                       const unsigned short* __restrict__ X,
                       unsigned short* __restrict__ Gn,
                       unsigned short* __restrict__ egon, unsigned short* __restrict__ ten) {
    int n = (blockIdx.x * 256 + threadIdx.x) >> 6;
    if (n >= NN) return;
    int lane = threadIdx.x & 63;
    int q = lane >> 4;
    int l = lane & 15;
    int f = l >> 2;
    int2 se = row_se[n];
    int r0 = __builtin_amdgcn_readfirstlane(se.x);
    int r1 = __builtin_amdgcn_readfirstlane(se.y);
    int deg = r1 - r0;
    if (deg <= 8) {
        if (deg <= 4)
            iter_body<FLAGS, 1>(n, lane, q, l, f, r0, r1, svals, G, te,
                                csr_tail, A4, out, X, Gn, egon, ten);
        else
            iter_body<FLAGS, 2>(n, lane, q, l, f, r0, r1, svals, G, te,
                                csr_tail, A4, out, X, Gn, egon, ten);
    } else {
        if (deg <= 12)
            iter_body<FLAGS, 3>(n, lane, q, l, f, r0, r1, svals, G, te,
                                csr_tail, A4, out, X, Gn, egon, ten);
        else
            iter_body<FLAGS, 4>(n, lane, q, l, f, r0, r1, svals, G, te,
                                csr_tail, A4, out, X, Gn, egon, ten);
    }
}

extern "C" void kernel_launch(void* const* d_in, const int* in_sizes, int n_in,
                              void* d_out, int out_size, void* d_ws, size_t ws_size,
                              hipStream_t stream) {
    const float* eu = (const float*)d_in[0];
    const float* ei = (const float*)d_in[1];
    const int* head = (const int*)d_in[2];
    const int* tail = (const int*)d_in[3];
    float* out = (float*)d_out;   // holds init until it3's 3-term mean (FL_FIN)

    // workspace layout — ~124 MB (16B-aligned first).
    // svals/A4/csr_tail sized by the PADDED edge space NPAD (R20 fix).
    // bin (6.4 MB packed, CSR-build scratch) aliases A4 (dead before A4 write).
    float* A4 = (float*)d_ws;                               // 25.6 MB (NPAD*4)
    float* d4a = A4 + (size_t)NPAD * 4;                     // 1.6 MB (it0 seed only)
    unsigned short* svals = (unsigned short*)(d4a + (size_t)NN * 4);  // 12.8 MB (NPAD*4)
    unsigned short* ego_a = svals + (size_t)NPAD * 4;       // 12.8 MB (raw)
    unsigned short* te_a  = ego_a + (size_t)NN * DIM_;      // 12.8 MB
    unsigned short* ego_b = te_a + (size_t)NN * DIM_;       // 12.8 MB (raw fn1)
    unsigned short* te_b  = ego_b + (size_t)NN * DIM_;      // 12.8 MB
    unsigned short* Ga    = te_b + (size_t)NN * DIM_;       // 12.8 MB
    unsigned short* Gb    = Ga + (size_t)NN * DIM_;         // 12.8 MB
    int* csr_tail = (int*)(Gb + (size_t)NN * DIM_);         // 6.4 MB (NPAD)
    int2* row_se = (int2*)(csr_tail + (size_t)NPAD);        // 0.8 MB
    int* cursor = (int*)(row_se + NN);                      // NBLK
    int* bin = (int*)A4;                                    // 6.4 MB alias

    const int node_blocks = ceil_div(NN * DIM_, 256);      // 25000
    const int wave_blocks = ceil_div(NN * 64, 256);        // 25000

    // padded-bucket CSR build + d0 = 2/sqrt(deg) seed (rowsum0 = 0.25*deg)
    hipMemsetAsync(cursor, 0, NBLK * sizeof(int), stream);
    k_binscat<<<NBLK, 256, 0, stream>>>(head, tail, cursor, bin);
    k_bucket<<<NBLK, 256, 0, stream>>>(bin, cursor, row_se, (float4*)d4a, csr_tail);

    // init AFTER csr build: ego_a raw, te_a, G0 = ego_a*d0 -> Ga, out = init
    k_init<<<node_blocks, 256, 0, stream>>>(eu, ei, d4a, ego_a, te_a, Ga, out);

    // it0: walk Ga (uniform weights cancel in norm); scores vs te_a:
    // A1 = 1 + s0 (store), svals_1; epilogue G1 = ego_a*d1 -> Gb.
    k_iter<FL_SVC | FL_SC | FL_ACONST | FL_ASTORE | FL_GN><<<wave_blocks, 256, 0, stream>>>(
        svals, Ga, te_a, row_se, csr_tail, A4, out, ego_a, Gb, ego_b, te_b);

    // it1: walk Gb with svals_1; fn1 -> ego_b(raw) + te_b; scores vs te_a:
    // A2 = A1 + s1 (store), svals_2; epilogue G2 = fn1*d2 -> Ga.
    k_iter<FL_SC | FL_ASTORE | FL_NEXT><<<wave_blocks, 256, 0, stream>>>(
        svals, Gb, te_a, row_se, csr_tail, A4, out, ego_a, Ga, ego_b, te_b);

    // it2: walk Ga with svals_2; scores vs te_b: A3 = A2 + s2 (store dead),
    // svals_3; epilogue G3 = ego_b*d3 -> Gb.
    k_iter<FL_SC | FL_GN><<<wave_blocks, 256, 0, stream>>>(
        svals, Ga, te_b, row_se, csr_tail, A4, out, ego_b, Gb, ego_b, te_b);

    // it3: walk Gb with svals_3; no scores; out = (init + fn1 + fn3)/3.
    k_iter<FL_FIN><<<wave_blocks, 256, 0, stream>>>(
        svals, Gb, te_b, row_se, csr_tail, A4, out, ego_b, Ga, ego_b, te_b);
}

// Round 10
// 341.406 us; speedup vs baseline: 1.1179x; 1.0019x over previous
//
#include <hip/hip_runtime.h>
#include <hip/hip_bf16.h>

// DGCF forward, MI355X. f32 in/out.
// R11-R20: bucketed->padded CSR build, fused walk+scores+softmax+D, pipelined
// chunks, bf16 tables, dot2bf, pre-scaled gather tables G = x*d.
// R21: 4 nodes per wave (16 lanes/node, lane = 16g + l16, dims 4*l16..+3,
// factor f = l16>>2). Deletes the q-slot acc reduce (8 shfl), accs reduce,
// GN d-shfl, FIN/NEXT redistribute; row stores become ushort4/float4.
// Loop runs to wave-uniform maxdeg (shfl-max) with per-lane validity masks.
#define NUSER 50000
#define NITEM 50000
#define NN    100000          // NUSER+NITEM
#define NNZ_  1000000
#define DIM_  64
#define NBLK  391             // ceil_div(NN,256) == bucket count
#define EPB   2560            // edges per scatter block (391*2560 >= NNZ)
#define BINC  4096            // per-bucket window capacity (mean 2560, +30 sigma)
#define NPAD  (NBLK * BINC)   // padded edge-index space (1,601,536)

#define FL_SVC    1   // walk weights uniform (it0; constant cancels in norm)
#define FL_SC     2   // fused scores: dot(fn, te[tail]) -> A -> softmax -> svals
#define FL_NEXT   8   // write ego_next(raw) / te_next / Gnext(from regs)
#define FL_FIN    16  // out = (out + X_row + fn) / 3
#define FL_ACONST 32  // scores: A_old == 1
#define FL_ASTORE 64  // scores: store A_new
#define FL_GN     128 // build Gnext = X_row * d  (X loaded, d from scores)

static inline int ceil_div(int a, int b) { return (a + b - 1) / b; }

static __device__ inline float bf2f(unsigned short u) {
    return __uint_as_float(((unsigned int)u) << 16);
}
static __device__ inline unsigned short f2bf(float f) {
    unsigned int x = __float_as_uint(f);
    x += 0x7fffu + ((x >> 16) & 1u);
    return (unsigned short)(x >> 16);
}

// packed bf16x2 dot: c += a.lo*b.lo + a.hi*b.hi (hw v_dot2_f32_bf16 if present)
#if __has_builtin(__builtin_amdgcn_fdot2_f32_bf16)
typedef __bf16 bf16x2_t __attribute__((ext_vector_type(2)));
static __device__ inline float dot2bf(unsigned int a, unsigned int b, float c) {
    return __builtin_amdgcn_fdot2_f32_bf16(__builtin_bit_cast(bf16x2_t, a),
                                           __builtin_bit_cast(bf16x2_t, b), c, false);
}
#else
static __device__ inline float dot2bf(unsigned int a, unsigned int b, float c) {
    return c + bf2f((unsigned short)(a & 0xffffu)) * bf2f((unsigned short)(b & 0xffffu))
             + bf2f((unsigned short)(a >> 16)) * bf2f((unsigned short)(b >> 16));
}
#endif

// ---- padded-bucket CSR build (once per launch) ----
__global__ void k_binscat(const int* __restrict__ head, const int* __restrict__ tail,
                          int* __restrict__ cursor, int* __restrict__ bin) {
    __shared__ int cnt[NBLK];
    __shared__ int chunk[NBLK];
    int tid = threadIdx.x;
    for (int i = tid; i < NBLK; i += 256) cnt[i] = 0;
    __syncthreads();
    int e0 = blockIdx.x * EPB;
    int e1 = min(e0 + EPB, NNZ_);
    for (int e = e0 + tid; e < e1; e += 256)
        atomicAdd(&cnt[head[e] >> 8], 1);
    __syncthreads();
    for (int i = tid; i < NBLK; i += 256) {
        chunk[i] = cnt[i] ? (i * BINC + atomicAdd(&cursor[i], cnt[i])) : 0;
        cnt[i] = 0;   // reuse as local cursor
    }
    __syncthreads();
    for (int e = e0 + tid; e < e1; e += 256) {
        int h = head[e], t = tail[e];
        int b = h >> 8;
        int off = atomicAdd(&cnt[b], 1);
        bin[chunk[b] + off] = t | ((h & 255) << 20);   // t < 2^17, hl < 2^8
    }
}

__global__ void k_bucket(const int* __restrict__ bin, const int* __restrict__ cursor,
                         int2* __restrict__ row_se, float4* __restrict__ d4a,
                         int* __restrict__ csr_tail) {
    __shared__ int deg[256];
    __shared__ int sh[256];
    __shared__ int cur[256];
    int tid = threadIdx.x;
    int b = blockIdx.x;
    int n0 = b << 8;
    int e0 = b * BINC, e1 = e0 + cursor[b];
    deg[tid] = 0;
    __syncthreads();
    for (int e = e0 + tid; e < e1; e += 256)
        atomicAdd(&deg[bin[e] >> 20], 1);
    __syncthreads();
    int myDeg = deg[tid];
    sh[tid] = myDeg;
    __syncthreads();
    for (int off = 1; off < 256; off <<= 1) {
        int u = 0;
        if (tid >= off) u = sh[tid - off];
        __syncthreads();
        sh[tid] += u;
        __syncthreads();
    }
    int loff = sh[tid] - myDeg;   // exclusive local offset
    int start = b * BINC + loff;  // csr window shares the BINC stride
    int n = n0 + tid;
    if (n < NN) {
        row_se[n] = make_int2(start, start + myDeg);
        float dd = (myDeg > 0) ? 2.0f / sqrtf((float)myDeg) : 0.0f;
        d4a[n] = make_float4(dd, dd, dd, dd);
    }
    cur[tid] = start;
    __syncthreads();
    for (int e = e0 + tid; e < e1; e += 256) {
        int p = bin[e];
        int pos = atomicAdd(&cur[p >> 20], 1);
        csr_tail[pos] = p & 0xFFFFF;
    }
}

// ego = raw bf16; te = tanh(l2norm chunk16); G0 = ego*d0; out = ego f32.
__global__ void k_init(const float* __restrict__ eu, const float* __restrict__ ei,
                       const float* __restrict__ d4a,   // viewed as float[NN*4]
                       unsigned short* __restrict__ ego, unsigned short* __restrict__ te,
                       unsigned short* __restrict__ G0, float* __restrict__ out) {
    int i = blockIdx.x * 256 + threadIdx.x;
    if (i >= NN * DIM_) return;
    float v = (i < NUSER * DIM_) ? eu[i] : ei[i - NUSER * DIM_];
    out[i] = v;
    ego[i] = f2bf(v);
    G0[i] = f2bf(v * d4a[i >> 4]);   // i>>4 == n*4 + f
    float s = v * v;
    s += __shfl_xor(s, 1); s += __shfl_xor(s, 2);
    s += __shfl_xor(s, 4); s += __shfl_xor(s, 8);
    float nrm = v / fmaxf(sqrtf(s), 1e-12f);
    float ex = __expf(2.0f * nrm);
    te[i] = f2bf((ex - 1.0f) / (ex + 1.0f));
}

// ---- fused walk + scores: 4 nodes per wave, 16 lanes per node ----
// lane = 16*g + l16; node n = wave_base + g; lane owns dims 4*l16..4*l16+3
// (all inside factor f = l16>>2). All per-node reduces are xor 1,2 (factor)
// and 4,8 (across factors) — group-local. Loop to wave-uniform maxdeg with
// per-lane masks; chunk0 = 8 edges cached (te reused by scores), remainder
// in pipelined 4-edge chunks.
template<int FLAGS>
__global__ void k_iter(unsigned short* __restrict__ svals,
                       const unsigned short* __restrict__ G,
                       const unsigned short* __restrict__ te,
                       const int2* __restrict__ row_se, const int* __restrict__ csr_tail,
                       float* __restrict__ A4,
                       float* __restrict__ out,
                       const unsigned short* __restrict__ X,   // raw row source (GN / FIN)
                       unsigned short* __restrict__ Gn,
                       unsigned short* __restrict__ egon, unsigned short* __restrict__ ten)
{
    int n = (blockIdx.x * 256 + threadIdx.x) >> 4;   // node per 16-lane group
    if (n >= NN) return;
    int l16 = threadIdx.x & 15;
    int f = l16 >> 2;
    int2 se = row_se[n];
    int r0 = se.x;
    int deg = se.y - se.x;
    // wave-uniform max degree over the 4 groups
    int m = deg;
    m = max(m, __shfl_xor(m, 16));
    m = max(m, __shfl_xor(m, 32));
    int maxdeg = __builtin_amdgcn_readfirstlane(m);

    float ax = 0.f, ay = 0.f, az = 0.f, aw = 0.f;

    // ---- chunk 0: edges r0..r0+7 (te cached for the scores phase) ----
    int ct[8]; float cw[8]; float ca[8]; uint2 cv[8];
#pragma unroll
    for (int j = 0; j < 8; ++j) {
        bool v = (j < deg);
        int ic = v ? (r0 + j) : r0;
        int t = csr_tail[ic];
        ct[j] = v ? t : 0;            // padding holes are uninitialized
        float w;
        if (FLAGS & FL_SVC) w = 1.0f;
        else w = bf2f(svals[ic * 4 + f]);
        cw[j] = v ? w : 0.f;
        if ((FLAGS & FL_SC) && !(FLAGS & FL_ACONST))
            ca[j] = A4[ic * 4 + f];
    }
#pragma unroll
    for (int j = 0; j < 8; ++j) {
        if (FLAGS & FL_SC)
            cv[j] = *(const uint2*)(te + ct[j] * 64 + 4 * l16);
    }
#pragma unroll
    for (int j = 0; j < 8; ++j) {
        ushort4 u = *(const ushort4*)(G + ct[j] * 64 + 4 * l16);
        ax += cw[j] * bf2f(u.x); ay += cw[j] * bf2f(u.y);
        az += cw[j] * bf2f(u.z); aw += cw[j] * bf2f(u.w);
    }

    // ---- remainder (maxdeg > 8): pipelined 4-edge chunks ----
    for (int kb = 8; kb < maxdeg; kb += 4) {
        int tj[4]; float wj[4];
#pragma unroll
        for (int j = 0; j < 4; ++j) {
            int jj = kb + j;
            bool v = (jj < deg);
            int ic = v ? (r0 + jj) : r0;
            int t = csr_tail[ic];
            tj[j] = v ? t : 0;
            float w;
            if (FLAGS & FL_SVC) w = 1.0f;
            else w = bf2f(svals[ic * 4 + f]);
            wj[j] = v ? w : 0.f;
        }
#pragma unroll
        for (int j = 0; j < 4; ++j) {
            ushort4 u = *(const ushort4*)(G + tj[j] * 64 + 4 * l16);
            ax += wj[j] * bf2f(u.x); ay += wj[j] * bf2f(u.y);
            az += wj[j] * bf2f(u.z); aw += wj[j] * bf2f(u.w);
        }
    }

    // accumulators are already complete (no cross-slot reduce!)
    // l2 norm over the factor's 16 dims: reduce over the factor's 4 lanes
    float s = ax * ax + ay * ay + az * az + aw * aw;
    s += __shfl_xor(s, 1); s += __shfl_xor(s, 2);
    float inv = 1.0f / fmaxf(sqrtf(s), 1e-12f);
    float fx = ax * inv, fy = ay * inv, fz = az * inv, fw = aw * inv;

    int base = n * 64 + 4 * l16;
    if (FLAGS & FL_FIN) {
        // out holds init; X row n holds bf16 fn1 -> 3-term mean (float4 RMW)
        float4* po = (float4*)(out + base);
        float4 ov = *po;
        ushort4 xv = *(const ushort4*)(X + base);
        ov.x = (ov.x + bf2f(xv.x) + fx) * (1.0f / 3.0f);
        ov.y = (ov.y + bf2f(xv.y) + fy) * (1.0f / 3.0f);
        ov.z = (ov.z + bf2f(xv.z) + fz) * (1.0f / 3.0f);
        ov.w = (ov.w + bf2f(xv.w) + fw) * (1.0f / 3.0f);
        *po = ov;
    }
    if (FLAGS & FL_NEXT) {
        ushort4 o;
        o.x = f2bf(fx); o.y = f2bf(fy); o.z = f2bf(fz); o.w = f2bf(fw);
        *(ushort4*)(egon + base) = o;
        float e0 = __expf(2.0f * fx), e1 = __expf(2.0f * fy);
        float e2 = __expf(2.0f * fz), e3 = __expf(2.0f * fw);
        ushort4 p;
        p.x = f2bf((e0 - 1.0f) / (e0 + 1.0f)); p.y = f2bf((e1 - 1.0f) / (e1 + 1.0f));
        p.z = f2bf((e2 - 1.0f) / (e2 + 1.0f)); p.w = f2bf((e3 - 1.0f) / (e3 + 1.0f));
        *(ushort4*)(ten + base) = p;
    }

    float accs = 0.f;   // rowsum of svals for factor f (replicated in-factor)
    if (FLAGS & FL_SC) {
        unsigned int p01 = ((unsigned int)f2bf(fy) << 16) | f2bf(fx);
        unsigned int p23 = ((unsigned int)f2bf(fw) << 16) | f2bf(fz);
        // cached chunk 0: pure register compute
#pragma unroll
        for (int j = 0; j < 8; ++j) {
            bool v = (j < deg);
            int i = r0 + j;
            float dot = dot2bf(cv[j].y, p23, dot2bf(cv[j].x, p01, 0.0f));
            dot += __shfl_xor(dot, 1); dot += __shfl_xor(dot, 2);
            float a = (FLAGS & FL_ACONST) ? 1.0f : ca[j];
            a += dot;
            float ex = __expf(a);
            float sum = ex;
            sum += __shfl_xor(sum, 4); sum += __shfl_xor(sum, 8);
            float sv = ex / sum;
            if (v && (l16 & 3) == 0) {
                if (FLAGS & FL_ASTORE) A4[i * 4 + f] = a;
                svals[i * 4 + f] = f2bf(sv);
            }
            accs += v ? sv : 0.f;
        }
        // remainder chunks: pipelined re-gather of tails/A4 -> te
        for (int kb = 8; kb < maxdeg; kb += 4) {
            int tj[4]; float aj[4]; uint2 vj[4];
#pragma unroll
            for (int j = 0; j < 4; ++j) {
                int jj = kb + j;
                bool v = (jj < deg);
                int ic = v ? (r0 + jj) : r0;
                int t = csr_tail[ic];
                tj[j] = v ? t : 0;
                if (!(FLAGS & FL_ACONST)) aj[j] = A4[ic * 4 + f];
            }
#pragma unroll
            for (int j = 0; j < 4; ++j)
                vj[j] = *(const uint2*)(te + tj[j] * 64 + 4 * l16);
#pragma unroll
            for (int j = 0; j < 4; ++j) {
                int jj = kb + j;
                bool v = (jj < deg);
                int i = r0 + jj;
                float dot = dot2bf(vj[j].y, p23, dot2bf(vj[j].x, p01, 0.0f));
                dot += __shfl_xor(dot, 1); dot += __shfl_xor(dot, 2);
                float a = (FLAGS & FL_ACONST) ? 1.0f : aj[j];
                a += dot;
                float ex = __expf(a);
                float sum = ex;
                sum += __shfl_xor(sum, 4); sum += __shfl_xor(sum, 8);
                float sv = ex / sum;
                if (v && (l16 & 3) == 0) {
                    if (FLAGS & FL_ASTORE) A4[i * 4 + f] = a;
                    svals[i * 4 + f] = f2bf(sv);
                }
                accs += v ? sv : 0.f;
            }
        }
        // accs is already the full rowsum for factor f (no cross-slot reduce)
    }

    if (FLAGS & (FL_GN | FL_NEXT)) {
        float d = (accs > 0.f) ? 1.0f / sqrtf(fmaxf(accs, 1e-12f)) : 0.f;
        float sx, sy, sz, sw;
        if (FLAGS & FL_NEXT) { sx = fx; sy = fy; sz = fz; sw = fw; }
        else {
            ushort4 xv = *(const ushort4*)(X + base);
            sx = bf2f(xv.x); sy = bf2f(xv.y); sz = bf2f(xv.z); sw = bf2f(xv.w);
        }
        ushort4 o;
        o.x = f2bf(sx * d); o.y = f2bf(sy * d);
        o.z = f2bf(sz * d); o.w = f2bf(sw * d);
        *(ushort4*)(Gn + base) = o;
    }
}

extern "C" void kernel_launch(void* const* d_in, const int* in_sizes, int n_in,
                              void* d_out, int out_size, void* d_ws, size_t ws_size,
                              hipStream_t stream) {
    const float* eu = (const float*)d_in[0];
    const float* ei = (const float*)d_in[1];
    const int* head = (const int*)d_in[2];
    const int* tail = (const int*)d_in[3];
    float* out = (float*)d_out;   // holds init until it3's 3-term mean (FL_FIN)

    // workspace layout — ~124 MB (16B-aligned first).
    // svals/A4/csr_tail sized by the PADDED edge space NPAD.
    // bin (6.4 MB packed, CSR-build scratch) aliases A4 (dead before A4 write).
    float* A4 = (float*)d_ws;                               // 25.6 MB (NPAD*4)
    float* d4a = A4 + (size_t)NPAD * 4;                     // 1.6 MB (it0 seed only)
    unsigned short* svals = (unsigned short*)(d4a + (size_t)NN * 4);  // 12.8 MB (NPAD*4)
    unsigned short* ego_a = svals + (size_t)NPAD * 4;       // 12.8 MB (raw)
    unsigned short* te_a  = ego_a + (size_t)NN * DIM_;      // 12.8 MB
    unsigned short* ego_b = te_a + (size_t)NN * DIM_;       // 12.8 MB (raw fn1)
    unsigned short* te_b  = ego_b + (size_t)NN * DIM_;      // 12.8 MB
    unsigned short* Ga    = te_b + (size_t)NN * DIM_;       // 12.8 MB
    unsigned short* Gb    = Ga + (size_t)NN * DIM_;         // 12.8 MB
    int* csr_tail = (int*)(Gb + (size_t)NN * DIM_);         // 6.4 MB (NPAD)
    int2* row_se = (int2*)(csr_tail + (size_t)NPAD);        // 0.8 MB
    int* cursor = (int*)(row_se + NN);                      // NBLK
    int* bin = (int*)A4;                                    // 6.4 MB alias

    const int node_blocks = ceil_div(NN * DIM_, 256);      // 25000
    const int iter_blocks = ceil_div(NN * 16, 256);        // 6250

    // padded-bucket CSR build + d0 = 2/sqrt(deg) seed (rowsum0 = 0.25*deg)
    hipMemsetAsync(cursor, 0, NBLK * sizeof(int), stream);
    k_binscat<<<NBLK, 256, 0, stream>>>(head, tail, cursor, bin);
    k_bucket<<<NBLK, 256, 0, stream>>>(bin, cursor, row_se, (float4*)d4a, csr_tail);

    // init AFTER csr build: ego_a raw, te_a, G0 = ego_a*d0 -> Ga, out = init
    k_init<<<node_blocks, 256, 0, stream>>>(eu, ei, d4a, ego_a, te_a, Ga, out);

    // it0: walk Ga (uniform weights cancel in norm); scores vs te_a:
    // A1 = 1 + s0 (store), svals_1; epilogue G1 = ego_a*d1 -> Gb.
    k_iter<FL_SVC | FL_SC | FL_ACONST | FL_ASTORE | FL_GN><<<iter_blocks, 256, 0, stream>>>(
        svals, Ga, te_a, row_se, csr_tail, A4, out, ego_a, Gb, ego_b, te_b);

    // it1: walk Gb with svals_1; fn1 -> ego_b(raw) + te_b; scores vs te_a:
    // A2 = A1 + s1 (store), svals_2; epilogue G2 = fn1*d2 -> Ga.
    k_iter<FL_SC | FL_ASTORE | FL_NEXT><<<iter_blocks, 256, 0, stream>>>(
        svals, Gb, te_a, row_se, csr_tail, A4, out, ego_a, Ga, ego_b, te_b);

    // it2: walk Ga with svals_2; scores vs te_b: A3 = A2 + s2 (store dead),
    // svals_3; epilogue G3 = ego_b*d3 -> Gb.
    k_iter<FL_SC | FL_GN><<<iter_blocks, 256, 0, stream>>>(
        svals, Ga, te_b, row_se, csr_tail, A4, out, ego_b, Gb, ego_b, te_b);

    // it3: walk Gb with svals_3; no scores; out = (init + fn1 + fn3)/3.
    k_iter<FL_FIN><<<iter_blocks, 256, 0, stream>>>(
        svals, Gb, te_b, row_se, csr_tail, A4, out, ego_b, Ga, ego_b, te_b);
}

// Round 11
// 335.527 us; speedup vs baseline: 1.1375x; 1.0175x over previous
//
#include <hip/hip_runtime.h>
#include <hip/hip_bf16.h>

// DGCF forward, MI355X. f32 in/out.
// R11-R20: padded-bucket CSR build, fused walk+scores+softmax+D, pipelined
// deg-adaptive chunks (wave per node), bf16 tables, dot2bf, pre-scaled G=x*d.
// R21 (reverted): 4 nodes/wave cut instructions but dropped occupancy 58->39%
// and went latency-bound; wave-per-node + NJ dispatch is the better base.
// R22: merged per-edge record svA[i*4+f] = {lo16: sval bf16, hi16: A f16}.
// Level-0 loads drop 3->2 per edge slot (one record feeds walk AND scores);
// scores store 2->1 packed; A4 f32 array dies (-12.8 MB workspace).
#define NUSER 50000
#define NITEM 50000
#define NN    100000          // NUSER+NITEM
#define NNZ_  1000000
#define DIM_  64
#define NBLK  391             // ceil_div(NN,256) == bucket count
#define EPB   2560            // edges per scatter block (391*2560 >= NNZ)
#define BINC  4096            // per-bucket window capacity (mean 2560, +30 sigma)
#define NPAD  (NBLK * BINC)   // padded edge-index space (1,601,536)

#define FL_SVC    1   // walk weights uniform (it0; constant cancels in norm)
#define FL_SC     2   // fused scores: dot(fn, te[tail]) -> A -> softmax -> svA
#define FL_NEXT   8   // write ego_next(raw) / te_next / Gnext(from regs)
#define FL_FIN    16  // out = (out + X_row + fn) / 3
#define FL_ACONST 32  // scores: A_old == 1 (skip record load if also FL_SVC)
#define FL_GN     128 // build Gnext = X_row * d  (X loaded, d from scores)

static inline int ceil_div(int a, int b) { return (a + b - 1) / b; }

static __device__ inline float bf2f(unsigned short u) {
    return __uint_as_float(((unsigned int)u) << 16);
}
static __device__ inline unsigned short f2bf(float f) {
    unsigned int x = __float_as_uint(f);
    x += 0x7fffu + ((x >> 16) & 1u);
    return (unsigned short)(x >> 16);
}
static __device__ inline unsigned short f2h(float f) {
    _Float16 h = (_Float16)f;
    return __builtin_bit_cast(unsigned short, h);
}
static __device__ inline float h2f(unsigned short u) {
    return (float)__builtin_bit_cast(_Float16, u);
}

// packed bf16x2 dot: c += a.lo*b.lo + a.hi*b.hi (hw v_dot2_f32_bf16 if present)
#if __has_builtin(__builtin_amdgcn_fdot2_f32_bf16)
typedef __bf16 bf16x2_t __attribute__((ext_vector_type(2)));
static __device__ inline float dot2bf(unsigned int a, unsigned int b, float c) {
    return __builtin_amdgcn_fdot2_f32_bf16(__builtin_bit_cast(bf16x2_t, a),
                                           __builtin_bit_cast(bf16x2_t, b), c, false);
}
#else
static __device__ inline float dot2bf(unsigned int a, unsigned int b, float c) {
    return c + bf2f((unsigned short)(a & 0xffffu)) * bf2f((unsigned short)(b & 0xffffu))
             + bf2f((unsigned short)(a >> 16)) * bf2f((unsigned short)(b >> 16));
}
#endif

// ---- padded-bucket CSR build (once per launch) ----
__global__ void k_binscat(const int* __restrict__ head, const int* __restrict__ tail,
                          int* __restrict__ cursor, int* __restrict__ bin) {
    __shared__ int cnt[NBLK];
    __shared__ int chunk[NBLK];
    int tid = threadIdx.x;
    for (int i = tid; i < NBLK; i += 256) cnt[i] = 0;
    __syncthreads();
    int e0 = blockIdx.x * EPB;
    int e1 = min(e0 + EPB, NNZ_);
    for (int e = e0 + tid; e < e1; e += 256)
        atomicAdd(&cnt[head[e] >> 8], 1);
    __syncthreads();
    for (int i = tid; i < NBLK; i += 256) {
        chunk[i] = cnt[i] ? (i * BINC + atomicAdd(&cursor[i], cnt[i])) : 0;
        cnt[i] = 0;   // reuse as local cursor
    }
    __syncthreads();
    for (int e = e0 + tid; e < e1; e += 256) {
        int h = head[e], t = tail[e];
        int b = h >> 8;
        int off = atomicAdd(&cnt[b], 1);
        bin[chunk[b] + off] = t | ((h & 255) << 20);   // t < 2^17, hl < 2^8
    }
}

__global__ void k_bucket(const int* __restrict__ bin, const int* __restrict__ cursor,
                         int2* __restrict__ row_se, float4* __restrict__ d4a,
                         int* __restrict__ csr_tail) {
    __shared__ int deg[256];
    __shared__ int sh[256];
    __shared__ int cur[256];
    int tid = threadIdx.x;
    int b = blockIdx.x;
    int n0 = b << 8;
    int e0 = b * BINC, e1 = e0 + cursor[b];
    deg[tid] = 0;
    __syncthreads();
    for (int e = e0 + tid; e < e1; e += 256)
        atomicAdd(&deg[bin[e] >> 20], 1);
    __syncthreads();
    int myDeg = deg[tid];
    sh[tid] = myDeg;
    __syncthreads();
    for (int off = 1; off < 256; off <<= 1) {
        int u = 0;
        if (tid >= off) u = sh[tid - off];
        __syncthreads();
        sh[tid] += u;
        __syncthreads();
    }
    int loff = sh[tid] - myDeg;   // exclusive local offset
    int start = b * BINC + loff;  // csr window shares the BINC stride
    int n = n0 + tid;
    if (n < NN) {
        row_se[n] = make_int2(start, start + myDeg);
        float dd = (myDeg > 0) ? 2.0f / sqrtf((float)myDeg) : 0.0f;
        d4a[n] = make_float4(dd, dd, dd, dd);
    }
    cur[tid] = start;
    __syncthreads();
    for (int e = e0 + tid; e < e1; e += 256) {
        int p = bin[e];
        int pos = atomicAdd(&cur[p >> 20], 1);
        csr_tail[pos] = p & 0xFFFFF;
    }
}

// ego = raw bf16; te = tanh(l2norm chunk16); G0 = ego*d0; out = ego f32.
__global__ void k_init(const float* __restrict__ eu, const float* __restrict__ ei,
                       const float* __restrict__ d4a,   // viewed as float[NN*4]
                       unsigned short* __restrict__ ego, unsigned short* __restrict__ te,
                       unsigned short* __restrict__ G0, float* __restrict__ out) {
    int i = blockIdx.x * 256 + threadIdx.x;
    if (i >= NN * DIM_) return;
    float v = (i < NUSER * DIM_) ? eu[i] : ei[i - NUSER * DIM_];
    out[i] = v;
    ego[i] = f2bf(v);
    G0[i] = f2bf(v * d4a[i >> 4]);   // i>>4 == n*4 + f
    float s = v * v;
    s += __shfl_xor(s, 1); s += __shfl_xor(s, 2);
    s += __shfl_xor(s, 4); s += __shfl_xor(s, 8);
    float nrm = v / fmaxf(sqrtf(s), 1e-12f);
    float ex = __expf(2.0f * nrm);
    te[i] = f2bf((ex - 1.0f) / (ex + 1.0f));
}

// ---- fused walk + scores body, NJ = chunk depth in 4-edge steps ----
// lane = 16*q + l: q = edge slot (0..3), l = dim quad (dims 4l..4l+3), f = l>>2.
// Walk gathers the PRE-SCALED table G (w = sval only; it0 w = 1).
// Per-edge record svA[i*4+f]: lo16 = sval (bf16), hi16 = A (f16).
template<int FLAGS, int NJ>
static __device__ __forceinline__ void iter_body(
    int n, int lane, int q, int l, int f, int r0, int r1,
    unsigned int* __restrict__ svA,
    const unsigned short* __restrict__ G,
    const unsigned short* __restrict__ te,
    const int* __restrict__ csr_tail,
    float* __restrict__ out,
    const unsigned short* __restrict__ X,   // raw row source (GN / FIN)
    unsigned short* __restrict__ Gn,
    unsigned short* __restrict__ egon, unsigned short* __restrict__ ten)
{
    constexpr bool needRec = !(FLAGS & FL_SVC) || ((FLAGS & FL_SC) && !(FLAGS & FL_ACONST));
    float ax = 0.f, ay = 0.f, az = 0.f, aw = 0.f;

    // ---- chunk 0: edges r0+q+4j, j=0..NJ-1 (te cached for scores phase) ----
    int ct[NJ]; float cw[NJ]; unsigned int cr[NJ]; uint2 cv[NJ];
    int eb = r0 + q;
#pragma unroll
    for (int j = 0; j < NJ; ++j) {
        int i = eb + 4 * j;
        bool v = (i < r1);
        int ic = v ? i : r0;
        int t = csr_tail[ic];
        ct[j] = v ? t : 0;            // padding holes are uninitialized
        if (needRec) cr[j] = svA[ic * 4 + f];
        float w;
        if (FLAGS & FL_SVC) w = 1.0f;
        else w = bf2f((unsigned short)(cr[j] & 0xffffu));
        cw[j] = v ? w : 0.f;
    }
#pragma unroll
    for (int j = 0; j < NJ; ++j) {
        if (FLAGS & FL_SC)
            cv[j] = *(const uint2*)(te + ct[j] * 64 + 4 * l);
    }
#pragma unroll
    for (int j = 0; j < NJ; ++j) {
        ushort4 u = *(const ushort4*)(G + ct[j] * 64 + 4 * l);
        ax += cw[j] * bf2f(u.x); ay += cw[j] * bf2f(u.y);
        az += cw[j] * bf2f(u.z); aw += cw[j] * bf2f(u.w);
    }

    // ---- remainder chunks (deg > 16), only reachable in the NJ==4 arm ----
    if (NJ == 4) {
        for (int base = r0 + 16; base < r1; base += 16) {
            int tj[4]; float wj[4];
#pragma unroll
            for (int j = 0; j < 4; ++j) {
                int i = base + q + 4 * j;
                bool v = (i < r1);
                int ic = v ? i : r0;
                int t = csr_tail[ic];
                tj[j] = v ? t : 0;
                float w;
                if (FLAGS & FL_SVC) w = 1.0f;
                else w = bf2f((unsigned short)(svA[ic * 4 + f] & 0xffffu));
                wj[j] = v ? w : 0.f;
            }
#pragma unroll
            for (int j = 0; j < 4; ++j) {
                ushort4 u = *(const ushort4*)(G + tj[j] * 64 + 4 * l);
                ax += wj[j] * bf2f(u.x); ay += wj[j] * bf2f(u.y);
                az += wj[j] * bf2f(u.z); aw += wj[j] * bf2f(u.w);
            }
        }
    }

    // reduce over edge slots -> each lane holds full sums for its dim quad
    ax += __shfl_xor(ax, 16); ax += __shfl_xor(ax, 32);
    ay += __shfl_xor(ay, 16); ay += __shfl_xor(ay, 32);
    az += __shfl_xor(az, 16); az += __shfl_xor(az, 32);
    aw += __shfl_xor(aw, 16); aw += __shfl_xor(aw, 32);

    // l2 norm over the 16-dim factor chunk (quad layout: reduce over l&3)
    float s = ax * ax + ay * ay + az * az + aw * aw;
    s += __shfl_xor(s, 1); s += __shfl_xor(s, 2);
    float inv = 1.0f / fmaxf(sqrtf(s), 1e-12f);
    float fx = ax * inv, fy = ay * inv, fz = az * inv, fw = aw * inv;

    float y = 0.f;
    if (FLAGS & (FL_NEXT | FL_FIN)) {
        // redistribute: lane p takes dim p (= component p&3 of lane p>>2's quad)
        int src = lane >> 2;
        float t0r = __shfl(fx, src), t1r = __shfl(fy, src);
        float t2r = __shfl(fz, src), t3r = __shfl(fw, src);
        y = (lane & 2) ? ((lane & 1) ? t3r : t2r) : ((lane & 1) ? t1r : t0r);
        int base = n * 64 + lane;
        if (FLAGS & FL_FIN) {
            // out holds init; X row n holds bf16 fn1 -> 3-term mean
            out[base] = (out[base] + bf2f(X[base]) + y) * (1.0f / 3.0f);
        }
        if (FLAGS & FL_NEXT) {
            egon[base] = f2bf(y);
            float e2 = __expf(2.0f * y);
            ten[base] = f2bf((e2 - 1.0f) / (e2 + 1.0f));
        }
    }

    float accs = 0.f;   // rowsum of svals for this lane's factor f
    if (FLAGS & FL_SC) {
        // pack fn once per node: lane's 4 dims -> two bf16x2 dwords
        unsigned int p01 = ((unsigned int)f2bf(fy) << 16) | f2bf(fx);
        unsigned int p23 = ((unsigned int)f2bf(fw) << 16) | f2bf(fz);
        // cached chunk 0: pure register compute
#pragma unroll
        for (int j = 0; j < NJ; ++j) {
            int i = eb + 4 * j;
            bool v = (i < r1);
            float dot = dot2bf(cv[j].y, p23, dot2bf(cv[j].x, p01, 0.0f));
            dot += __shfl_xor(dot, 1); dot += __shfl_xor(dot, 2);
            float a = (FLAGS & FL_ACONST) ? 1.0f : h2f((unsigned short)(cr[j] >> 16));
            a += dot;
            float ex = __expf(a);
            float sum = ex;
            sum += __shfl_xor(sum, 4); sum += __shfl_xor(sum, 8);
            float sv = ex / sum;
            if (v && (l & 3) == 0)
                svA[i * 4 + f] = (unsigned int)f2bf(sv) | ((unsigned int)f2h(a) << 16);
            accs += v ? sv : 0.f;
        }
        // remainder chunks: pipelined re-gather of tails/records -> te
        if (NJ == 4) {
            for (int base = r0 + 16; base < r1; base += 16) {
                int tj[4]; float aj[4]; uint2 vj[4];
#pragma unroll
                for (int j = 0; j < 4; ++j) {
                    int i = base + q + 4 * j;
                    bool v = (i < r1);
                    int ic = v ? i : r0;
                    int t = csr_tail[ic];
                    tj[j] = v ? t : 0;
                    if (!(FLAGS & FL_ACONST))
                        aj[j] = h2f((unsigned short)(svA[ic * 4 + f] >> 16));
                }
#pragma unroll
                for (int j = 0; j < 4; ++j)
                    vj[j] = *(const uint2*)(te + tj[j] * 64 + 4 * l);
#pragma unroll
                for (int j = 0; j < 4; ++j) {
                    int i = base + q + 4 * j;
                    bool v = (i < r1);
                    float dot = dot2bf(vj[j].y, p23, dot2bf(vj[j].x, p01, 0.0f));
                    dot += __shfl_xor(dot, 1); dot += __shfl_xor(dot, 2);
                    float a = (FLAGS & FL_ACONST) ? 1.0f : aj[j];
                    a += dot;
                    float ex = __expf(a);
                    float sum = ex;
                    sum += __shfl_xor(sum, 4); sum += __shfl_xor(sum, 8);
                    float sv = ex / sum;
                    if (v && (l & 3) == 0)
                        svA[i * 4 + f] = (unsigned int)f2bf(sv) | ((unsigned int)f2h(a) << 16);
                    accs += v ? sv : 0.f;
                }
            }
        }
        // reduce over edge slots q (value replicated over the l&3 dups)
        accs += __shfl_xor(accs, 16); accs += __shfl_xor(accs, 32);
    }

    if (FLAGS & (FL_GN | FL_NEXT)) {
        // d for this lane's OUTPUT factor (dim = lane, factor = lane>>4):
        // accs for factor g lives on lane 4*g (and dups).
        float av = __shfl(accs, (lane >> 4) << 2);
        float d = (av > 0.f) ? 1.0f / sqrtf(fmaxf(av, 1e-12f)) : 0.f;
        int base = n * 64 + lane;
        float src = (FLAGS & FL_NEXT) ? y : bf2f(X[base]);
        Gn[base] = f2bf(src * d);
    }
}

// dispatcher: one wave per node; deg is wave-uniform (SGPR) -> scalar branch
template<int FLAGS>
__global__ void k_iter(unsigned int* __restrict__ svA,
                       const unsigned short* __restrict__ G,
                       const unsigned short* __restrict__ te,
                       const int2* __restrict__ row_se, const int* __restrict__ csr_tail,
                       float* __restrict__ out,
                       const unsigned short* __restrict__ X,
                       unsigned short* __restrict__ Gn,
                       unsigned short* __restrict__ egon, unsigned short* __restrict__ ten) {
    int n = (blockIdx.x * 256 + threadIdx.x) >> 6;
    if (n >= NN) return;
    int lane = threadIdx.x & 63;
    int q = lane >> 4;
    int l = lane & 15;
    int f = l >> 2;
    int2 se = row_se[n];
    int r0 = __builtin_amdgcn_readfirstlane(se.x);
    int r1 = __builtin_amdgcn_readfirstlane(se.y);
    int deg = r1 - r0;
    if (deg <= 8) {
        if (deg <= 4)
            iter_body<FLAGS, 1>(n, lane, q, l, f, r0, r1, svA, G, te,
                                csr_tail, out, X, Gn, egon, ten);
        else
            iter_body<FLAGS, 2>(n, lane, q, l, f, r0, r1, svA, G, te,
                                csr_tail, out, X, Gn, egon, ten);
    } else {
        if (deg <= 12)
            iter_body<FLAGS, 3>(n, lane, q, l, f, r0, r1, svA, G, te,
                                csr_tail, out, X, Gn, egon, ten);
        else
            iter_body<FLAGS, 4>(n, lane, q, l, f, r0, r1, svA, G, te,
                                csr_tail, out, X, Gn, egon, ten);
    }
}

extern "C" void kernel_launch(void* const* d_in, const int* in_sizes, int n_in,
                              void* d_out, int out_size, void* d_ws, size_t ws_size,
                              hipStream_t stream) {
    const float* eu = (const float*)d_in[0];
    const float* ei = (const float*)d_in[1];
    const int* head = (const int*)d_in[2];
    const int* tail = (const int*)d_in[3];
    float* out = (float*)d_out;   // holds init until it3's 3-term mean (FL_FIN)

    // workspace layout — ~111 MB (16B-aligned first).
    // svA = merged per-edge record (NPAD*4 uints). bin (6.4 MB) aliases svA
    // (bin dead after k_bucket; svA first written in it0's scores phase).
    unsigned int* svA = (unsigned int*)d_ws;                // 25.6 MB (NPAD*4)
    float* d4a = (float*)(svA + (size_t)NPAD * 4);          // 1.6 MB (it0 seed only)
    unsigned short* ego_a = (unsigned short*)(d4a + (size_t)NN * 4);  // 12.8 MB (raw)
    unsigned short* te_a  = ego_a + (size_t)NN * DIM_;      // 12.8 MB
    unsigned short* ego_b = te_a + (size_t)NN * DIM_;       // 12.8 MB (raw fn1)
    unsigned short* te_b  = ego_b + (size_t)NN * DIM_;      // 12.8 MB
    unsigned short* Ga    = te_b + (size_t)NN * DIM_;       // 12.8 MB
    unsigned short* Gb    = Ga + (size_t)NN * DIM_;         // 12.8 MB
    int* csr_tail = (int*)(Gb + (size_t)NN * DIM_);         // 6.4 MB (NPAD)
    int2* row_se = (int2*)(csr_tail + (size_t)NPAD);        // 0.8 MB
    int* cursor = (int*)(row_se + NN);                      // NBLK
    int* bin = (int*)svA;                                   // 6.4 MB alias

    const int node_blocks = ceil_div(NN * DIM_, 256);      // 25000
    const int wave_blocks = ceil_div(NN * 64, 256);        // 25000

    // padded-bucket CSR build + d0 = 2/sqrt(deg) seed (rowsum0 = 0.25*deg)
    hipMemsetAsync(cursor, 0, NBLK * sizeof(int), stream);
    k_binscat<<<NBLK, 256, 0, stream>>>(head, tail, cursor, bin);
    k_bucket<<<NBLK, 256, 0, stream>>>(bin, cursor, row_se, (float4*)d4a, csr_tail);

    // init AFTER csr build: ego_a raw, te_a, G0 = ego_a*d0 -> Ga, out = init
    k_init<<<node_blocks, 256, 0, stream>>>(eu, ei, d4a, ego_a, te_a, Ga, out);

    // it0: walk Ga (uniform weights cancel in norm); scores vs te_a:
    // A1 = 1 + s0, svals_1 -> svA (packed); epilogue G1 = ego_a*d1 -> Gb.
    k_iter<FL_SVC | FL_SC | FL_ACONST | FL_GN><<<wave_blocks, 256, 0, stream>>>(
        svA, Ga, te_a, row_se, csr_tail, out, ego_a, Gb, ego_b, te_b);

    // it1: walk Gb with svals_1; fn1 -> ego_b(raw) + te_b; scores vs te_a:
    // A2 = A1 + s1, svals_2 -> svA; epilogue G2 = fn1*d2 -> Ga.
    k_iter<FL_SC | FL_NEXT><<<wave_blocks, 256, 0, stream>>>(
        svA, Gb, te_a, row_se, csr_tail, out, ego_a, Ga, ego_b, te_b);

    // it2: walk Ga with svals_2; scores vs te_b: A3 = A2 + s2, svals_3 -> svA;
    // epilogue G3 = ego_b*d3 -> Gb.
    k_iter<FL_SC | FL_GN><<<wave_blocks, 256, 0, stream>>>(
        svA, Ga, te_b, row_se, csr_tail, out, ego_b, Gb, ego_b, te_b);

    // it3: walk Gb with svals_3; no scores; out = (init + fn1 + fn3)/3.
    k_iter<FL_FIN><<<wave_blocks, 256, 0, stream>>>(
        svA, Gb, te_b, row_se, csr_tail, out, ego_b, Ga, ego_b, te_b);
}